// Round 1
// baseline (5549.289 us; speedup 1.0000x reference)
//
#include <hip/hip_runtime.h>
#include <math.h>

namespace {

constexpr int kB   = 4;
constexpr int kN   = 1024;
constexpr int kDim = 768;
constexpr int kH   = 12;
constexpr int kGP  = 64;
constexpr int kHD  = 64;
constexpr int kBH  = kB * kH;
constexpr float kScale = 0.125f;  // HD^-0.5

// ---------- swizzled 64x64 f32 LDS tile (flat 4096 floats) ----------
// element (r, d) lives at r*64 + ((d/4) ^ (r&15))*4 + (d&3)
// -> float4 reads over d are contiguous & 16B aligned; column reads across
//    r hit distinct bank groups (<=2-way conflict).
__device__ __forceinline__ int swz(int r, int d) {
  return (r << 6) + (((((d >> 2) ^ (r & 15))) << 2) | (d & 3));
}

__device__ __forceinline__ void load_tile64(float* dst, const float* __restrict__ src, int tid) {
  #pragma unroll
  for (int t = tid; t < 1024; t += 256) {
    const int r = t >> 4;
    const int c = (t & 15) << 2;
    const float4 v4 = *(const float4*)(src + (r << 6) + c);
    *(float4*)(dst + swz(r, c)) = v4;
  }
}

// transposed store: dst[d][m] = src[m][d]
__device__ __forceinline__ void load_tile64_T(float* dst, const float* __restrict__ src, int tid) {
  #pragma unroll
  for (int t = tid; t < 1024; t += 256) {
    const int r = t >> 4;          // source row (m)
    const int c = (t & 15) << 2;   // source col (d)
    const float4 v4 = *(const float4*)(src + (r << 6) + c);
    dst[swz(c + 0, r)] = v4.x;
    dst[swz(c + 1, r)] = v4.y;
    dst[swz(c + 2, r)] = v4.z;
    dst[swz(c + 3, r)] = v4.w;
  }
}

// fused dual GEMM over d=0..63:
//   sa[i][j] += rowsQ[ty4+i][d] * colsK[tx4+j][d]
//   ga[i][j] += rowsG[ty4+i][d] * colsGm[tx4+j][d]
__device__ __forceinline__ void dual_gemm_64(const float* qn, const float* gn,
                                             const float* kt, const float* gm,
                                             int ty4, int tx4,
                                             float sa[4][4], float ga[4][4]) {
  #pragma unroll
  for (int d0 = 0; d0 < 64; d0 += 4) {
    float4 aq[4], ag[4];
    #pragma unroll
    for (int i = 0; i < 4; i++) {
      aq[i] = *(const float4*)(qn + swz(ty4 + i, d0));
      ag[i] = *(const float4*)(gn + swz(ty4 + i, d0));
    }
    #pragma unroll
    for (int j = 0; j < 4; j++) {
      const float4 bk = *(const float4*)(kt + swz(tx4 + j, d0));
      const float4 eg = *(const float4*)(gm + swz(tx4 + j, d0));
      #pragma unroll
      for (int i = 0; i < 4; i++) {
        sa[i][j] = fmaf(aq[i].x, bk.x, sa[i][j]);
        sa[i][j] = fmaf(aq[i].y, bk.y, sa[i][j]);
        sa[i][j] = fmaf(aq[i].z, bk.z, sa[i][j]);
        sa[i][j] = fmaf(aq[i].w, bk.w, sa[i][j]);
        ga[i][j] = fmaf(ag[i].x, eg.x, ga[i][j]);
        ga[i][j] = fmaf(ag[i].y, eg.y, ga[i][j]);
        ga[i][j] = fmaf(ag[i].z, eg.z, ga[i][j]);
        ga[i][j] = fmaf(ag[i].w, eg.w, ga[i][j]);
      }
    }
  }
}

// ---------------- K1: qkv = x @ W_qkv^T (+bias), scattered to q/k/v heads ---
__global__ __launch_bounds__(256) void k_qkv(const float* __restrict__ X,
                                             const float* __restrict__ W,
                                             const float* __restrict__ bias,
                                             float* __restrict__ qb,
                                             float* __restrict__ kb,
                                             float* __restrict__ vb) {
  __shared__ float As[32][132];
  __shared__ float Bs[32][132];
  const int bx = blockIdx.x;        // 0..17 over 2304 cols
  const int by = blockIdx.y;        // 0..31 over 4096 rows
  const int tid = threadIdx.x;
  const int tx = tid & 15, ty = tid >> 4;
  const int lrow = tid >> 3;
  const int lk = (tid & 7) << 2;
  float acc[8][8] = {};
  for (int k0 = 0; k0 < kDim; k0 += 32) {
    __syncthreads();
    #pragma unroll
    for (int rr = 0; rr < 4; rr++) {
      const int row = lrow + (rr << 5);
      const float4 av = *(const float4*)(X + (size_t)(by * 128 + row) * kDim + k0 + lk);
      As[lk + 0][row] = av.x; As[lk + 1][row] = av.y;
      As[lk + 2][row] = av.z; As[lk + 3][row] = av.w;
      const float4 bv = *(const float4*)(W + (size_t)(bx * 128 + row) * kDim + k0 + lk);
      Bs[lk + 0][row] = bv.x; Bs[lk + 1][row] = bv.y;
      Bs[lk + 2][row] = bv.z; Bs[lk + 3][row] = bv.w;
    }
    __syncthreads();
    #pragma unroll
    for (int k = 0; k < 32; k++) {
      const float4 a0 = *(const float4*)(&As[k][ty * 8]);
      const float4 a1 = *(const float4*)(&As[k][ty * 8 + 4]);
      const float4 b0 = *(const float4*)(&Bs[k][tx * 8]);
      const float4 b1 = *(const float4*)(&Bs[k][tx * 8 + 4]);
      const float av8[8] = {a0.x, a0.y, a0.z, a0.w, a1.x, a1.y, a1.z, a1.w};
      const float bv8[8] = {b0.x, b0.y, b0.z, b0.w, b1.x, b1.y, b1.z, b1.w};
      #pragma unroll
      for (int i = 0; i < 8; i++)
        #pragma unroll
        for (int j = 0; j < 8; j++)
          acc[i][j] = fmaf(av8[i], bv8[j], acc[i][j]);
    }
  }
  #pragma unroll
  for (int i = 0; i < 8; i++) {
    const int row = by * 128 + ty * 8 + i;
    const int b = row >> 10;
    const int n = row & 1023;
    #pragma unroll
    for (int j = 0; j < 8; j++) {
      const int col = bx * 128 + tx * 8 + j;
      const int part = col / 768;
      const int rem = col - part * 768;
      const int hh = rem >> 6;
      const int d = rem & 63;
      float* dst = (part == 0) ? qb : ((part == 1) ? kb : vb);
      dst[(size_t)((b * kH + hh) * kN + n) * kHD + d] = acc[i][j] + bias[col];
    }
  }
}

// ---------------- K2: gw = softmax(gelu(v @ gp[h]^T)) over GP=64 ------------
__global__ __launch_bounds__(256) void k_gw(const float* __restrict__ vb,
                                            const float* __restrict__ Wgp,
                                            float* __restrict__ gwb) {
  const int bh = blockIdx.x;
  const int h = bh % kH;
  const int n0 = blockIdx.y << 6;
  __shared__ float gps[64][65];
  __shared__ float vs[64][65];
  const int tid = threadIdx.x;
  #pragma unroll
  for (int t = tid; t < 1024; t += 256) {
    const int r = t >> 4;
    const int c = (t & 15) << 2;
    const float4 g4 = *(const float4*)(Wgp + h * 4096 + (r << 6) + c);
    gps[r][c] = g4.x; gps[r][c + 1] = g4.y; gps[r][c + 2] = g4.z; gps[r][c + 3] = g4.w;
    const float4 v4 = *(const float4*)(vb + (size_t)(bh * kN + n0 + r) * kHD + c);
    vs[r][c] = v4.x; vs[r][c + 1] = v4.y; vs[r][c + 2] = v4.z; vs[r][c + 3] = v4.w;
  }
  __syncthreads();
  const int w = tid >> 6;
  const int lane = tid & 63;
  for (int r = 0; r < 16; r++) {
    const int nl = (w << 4) + r;
    float acc = 0.f;
    #pragma unroll
    for (int d = 0; d < 64; d++) acc = fmaf(vs[nl][d], gps[lane][d], acc);
    const float u = 0.5f * acc * (1.0f + erff(acc * 0.70710678118654752f));  // exact GELU
    float mx = u;
    #pragma unroll
    for (int off = 32; off; off >>= 1) mx = fmaxf(mx, __shfl_xor(mx, off));
    const float e = __expf(u - mx);
    float s = e;
    #pragma unroll
    for (int off = 32; off; off >>= 1) s += __shfl_xor(s, off);
    gwb[(size_t)(bh * kN + n0 + nl) * kGP + lane] = e / s;
  }
}

// ---------------- K3: rdenom[n] = 1 / sum_m exp(scale*(q.k)*(gw.gw)) --------
__global__ __launch_bounds__(256) void k_denom(const float* __restrict__ qb,
                                               const float* __restrict__ kb,
                                               const float* __restrict__ gwb,
                                               float* __restrict__ rdenom) {
  const int bh = blockIdx.x;
  const int n0 = blockIdx.y << 6;
  __shared__ float qn[4096], gn[4096], kt[4096], gm[4096];
  const int tid = threadIdx.x;
  const int tx4 = (tid & 15) << 2, ty4 = (tid >> 4) << 2;

  load_tile64(qn, qb + (size_t)(bh * kN + n0) * kHD, tid);
  load_tile64(gn, gwb + (size_t)(bh * kN + n0) * kGP, tid);

  float dsum[4] = {};
  for (int m0 = 0; m0 < kN; m0 += 64) {
    __syncthreads();
    load_tile64(kt, kb + (size_t)(bh * kN + m0) * kHD, tid);
    load_tile64(gm, gwb + (size_t)(bh * kN + m0) * kGP, tid);
    __syncthreads();
    float sa[4][4] = {}, ga[4][4] = {};
    dual_gemm_64(qn, gn, kt, gm, ty4, tx4, sa, ga);
    #pragma unroll
    for (int i = 0; i < 4; i++)
      #pragma unroll
      for (int j = 0; j < 4; j++)
        dsum[i] += __expf(sa[i][j] * kScale * ga[i][j]);
  }
  __syncthreads();
  #pragma unroll
  for (int i = 0; i < 4; i++) kt[(ty4 + i) * 16 + (tid & 15)] = dsum[i];
  __syncthreads();
  if (tid < 64) {
    float s = 0.f;
    #pragma unroll
    for (int x = 0; x < 16; x++) s += kt[tid * 16 + x];
    rdenom[bh * kN + n0 + tid] = 1.0f / s;
  }
}

// ---------------- K4: rcol[m] = 1 / (sum_n A[n,m] + 1e-8) -------------------
__global__ __launch_bounds__(256) void k_colsum(const float* __restrict__ qb,
                                                const float* __restrict__ kb,
                                                const float* __restrict__ gwb,
                                                const float* __restrict__ rdenom,
                                                const float* __restrict__ alpha,
                                                float* __restrict__ rcolv) {
  const int bh = blockIdx.x;
  const int h = bh % kH;
  const int m0 = blockIdx.y << 6;
  __shared__ float kt[4096], gm[4096], qn[4096], gn[4096];
  __shared__ float rd[64];
  const int tid = threadIdx.x;
  const int tx4 = (tid & 15) << 2, ty4 = (tid >> 4) << 2;
  const float ah = 1.0f / (1.0f + __expf(-alpha[h]));
  const float om = 1.0f - ah;

  load_tile64(kt, kb + (size_t)(bh * kN + m0) * kHD, tid);
  load_tile64(gm, gwb + (size_t)(bh * kN + m0) * kGP, tid);

  float csum[4] = {};
  for (int r0 = 0; r0 < kN; r0 += 64) {
    __syncthreads();
    load_tile64(qn, qb + (size_t)(bh * kN + r0) * kHD, tid);
    load_tile64(gn, gwb + (size_t)(bh * kN + r0) * kGP, tid);
    if (tid < 64) rd[tid] = rdenom[bh * kN + r0 + tid];
    __syncthreads();
    float sa[4][4] = {}, ga[4][4] = {};
    dual_gemm_64(qn, gn, kt, gm, ty4, tx4, sa, ga);
    #pragma unroll
    for (int i = 0; i < 4; i++) {
      const float rdi = rd[ty4 + i];
      #pragma unroll
      for (int j = 0; j < 4; j++) {
        const float g = ga[i][j];
        const float p = __expf(sa[i][j] * kScale * g) * rdi;
        csum[j] += om * p + ah * g;
      }
    }
  }
  __syncthreads();
  #pragma unroll
  for (int j = 0; j < 4; j++) qn[(tx4 + j) * 16 + (tid >> 4)] = csum[j];
  __syncthreads();
  if (tid < 64) {
    float s = 0.f;
    #pragma unroll
    for (int x = 0; x < 16; x++) s += qn[tid * 16 + x];
    rcolv[bh * kN + m0 + tid] = 1.0f / (s + 1e-8f);
  }
}

// ---------------- K5: ctx[b,n,h*64+d] = sum_m (A[n,m]*rcol[m]) * v[m,d] -----
__global__ __launch_bounds__(256) void k_out(const float* __restrict__ qb,
                                             const float* __restrict__ kb,
                                             const float* __restrict__ vb,
                                             const float* __restrict__ gwb,
                                             const float* __restrict__ rdenom,
                                             const float* __restrict__ rcolv,
                                             const float* __restrict__ alpha,
                                             float* __restrict__ ctx) {
  const int bh = blockIdx.x;
  const int h = bh % kH;
  const int b = bh / kH;
  const int n0 = blockIdx.y << 6;
  __shared__ float qn[4096], gn[4096], tC[4096], tD[4096];
  __shared__ float rcl[64];
  const int tid = threadIdx.x;
  const int tx4 = (tid & 15) << 2, ty4 = (tid >> 4) << 2;
  const float ah = 1.0f / (1.0f + __expf(-alpha[h]));
  const float om = 1.0f - ah;

  load_tile64(qn, qb + (size_t)(bh * kN + n0) * kHD, tid);
  load_tile64(gn, gwb + (size_t)(bh * kN + n0) * kGP, tid);
  float rdn[4];
  #pragma unroll
  for (int i = 0; i < 4; i++) rdn[i] = rdenom[bh * kN + n0 + ty4 + i];

  float oacc[4][4] = {};
  for (int m0 = 0; m0 < kN; m0 += 64) {
    __syncthreads();
    load_tile64(tC, kb + (size_t)(bh * kN + m0) * kHD, tid);   // K rows
    load_tile64(tD, gwb + (size_t)(bh * kN + m0) * kGP, tid);  // gw_m rows
    if (tid < 64) rcl[tid] = rcolv[bh * kN + m0 + tid];
    __syncthreads();
    float sa[4][4] = {}, ga[4][4] = {};
    dual_gemm_64(qn, gn, tC, tD, ty4, tx4, sa, ga);
    __syncthreads();
    // tC := v^T tile; tD := A*rcol tile (both operands of phase-2 GEMM)
    load_tile64_T(tC, vb + (size_t)(bh * kN + m0) * kHD, tid);
    #pragma unroll
    for (int i = 0; i < 4; i++)
      #pragma unroll
      for (int j = 0; j < 4; j++) {
        const float g = ga[i][j];
        const float p = __expf(sa[i][j] * kScale * g) * rdn[i];
        tD[swz(ty4 + i, tx4 + j)] = (om * p + ah * g) * rcl[tx4 + j];
      }
    __syncthreads();
    #pragma unroll
    for (int mm = 0; mm < 64; mm += 4) {
      float4 a4[4], v4[4];
      #pragma unroll
      for (int i = 0; i < 4; i++) a4[i] = *(const float4*)(tD + swz(ty4 + i, mm));
      #pragma unroll
      for (int j = 0; j < 4; j++) v4[j] = *(const float4*)(tC + swz(tx4 + j, mm));
      #pragma unroll
      for (int i = 0; i < 4; i++)
        #pragma unroll
        for (int j = 0; j < 4; j++) {
          oacc[i][j] = fmaf(a4[i].x, v4[j].x, oacc[i][j]);
          oacc[i][j] = fmaf(a4[i].y, v4[j].y, oacc[i][j]);
          oacc[i][j] = fmaf(a4[i].z, v4[j].z, oacc[i][j]);
          oacc[i][j] = fmaf(a4[i].w, v4[j].w, oacc[i][j]);
        }
    }
  }
  #pragma unroll
  for (int i = 0; i < 4; i++) {
    const int n = n0 + ty4 + i;
    float4 o4 = make_float4(oacc[i][0], oacc[i][1], oacc[i][2], oacc[i][3]);
    *(float4*)(ctx + (size_t)(b * kN + n) * kDim + h * kHD + tx4) = o4;
  }
}

// ---------------- K6: out = ctx @ W_proj^T + b_proj -------------------------
__global__ __launch_bounds__(256) void k_proj(const float* __restrict__ Xc,
                                              const float* __restrict__ W,
                                              const float* __restrict__ bias,
                                              float* __restrict__ out) {
  __shared__ float As[32][132];
  __shared__ float Bs[32][132];
  const int bx = blockIdx.x;  // 0..5 over 768 cols
  const int by = blockIdx.y;  // 0..31 over 4096 rows
  const int tid = threadIdx.x;
  const int tx = tid & 15, ty = tid >> 4;
  const int lrow = tid >> 3;
  const int lk = (tid & 7) << 2;
  float acc[8][8] = {};
  for (int k0 = 0; k0 < kDim; k0 += 32) {
    __syncthreads();
    #pragma unroll
    for (int rr = 0; rr < 4; rr++) {
      const int row = lrow + (rr << 5);
      const float4 av = *(const float4*)(Xc + (size_t)(by * 128 + row) * kDim + k0 + lk);
      As[lk + 0][row] = av.x; As[lk + 1][row] = av.y;
      As[lk + 2][row] = av.z; As[lk + 3][row] = av.w;
      const float4 bv = *(const float4*)(W + (size_t)(bx * 128 + row) * kDim + k0 + lk);
      Bs[lk + 0][row] = bv.x; Bs[lk + 1][row] = bv.y;
      Bs[lk + 2][row] = bv.z; Bs[lk + 3][row] = bv.w;
    }
    __syncthreads();
    #pragma unroll
    for (int k = 0; k < 32; k++) {
      const float4 a0 = *(const float4*)(&As[k][ty * 8]);
      const float4 a1 = *(const float4*)(&As[k][ty * 8 + 4]);
      const float4 b0 = *(const float4*)(&Bs[k][tx * 8]);
      const float4 b1 = *(const float4*)(&Bs[k][tx * 8 + 4]);
      const float av8[8] = {a0.x, a0.y, a0.z, a0.w, a1.x, a1.y, a1.z, a1.w};
      const float bv8[8] = {b0.x, b0.y, b0.z, b0.w, b1.x, b1.y, b1.z, b1.w};
      #pragma unroll
      for (int i = 0; i < 8; i++)
        #pragma unroll
        for (int j = 0; j < 8; j++)
          acc[i][j] = fmaf(av8[i], bv8[j], acc[i][j]);
    }
  }
  #pragma unroll
  for (int i = 0; i < 8; i++) {
    const int row = by * 128 + ty * 8 + i;
    #pragma unroll
    for (int j = 0; j < 8; j++) {
      const int col = bx * 128 + tx * 8 + j;
      out[(size_t)row * kDim + col] = acc[i][j] + bias[col];
    }
  }
}

}  // namespace

extern "C" void kernel_launch(void* const* d_in, const int* in_sizes, int n_in,
                              void* d_out, int out_size, void* d_ws, size_t ws_size,
                              hipStream_t stream) {
  const float* x     = (const float*)d_in[0];
  const float* Wqkv  = (const float*)d_in[1];
  const float* bqkv  = (const float*)d_in[2];
  const float* Wgp   = (const float*)d_in[3];
  const float* alpha = (const float*)d_in[4];
  const float* Wproj = (const float*)d_in[5];
  const float* bproj = (const float*)d_in[6];
  float* out = (float*)d_out;
  float* ws  = (float*)d_ws;

  const size_t head_elems = (size_t)kBH * kN * kHD;  // 3,145,728
  float* qb     = ws;
  float* kb     = qb + head_elems;
  float* vb     = kb + head_elems;
  float* gwb    = vb + head_elems;
  float* rdenom = gwb + head_elems;
  float* rcolv  = rdenom + (size_t)kBH * kN;
  float* ctx    = rcolv + (size_t)kBH * kN;
  // total ws use: ~63.3 MB (5*12.6MB + small)

  k_qkv  <<<dim3(2304 / 128, 4096 / 128), 256, 0, stream>>>(x, Wqkv, bqkv, qb, kb, vb);
  k_gw   <<<dim3(kBH, kN / 64), 256, 0, stream>>>(vb, Wgp, gwb);
  k_denom<<<dim3(kBH, kN / 64), 256, 0, stream>>>(qb, kb, gwb, rdenom);
  k_colsum<<<dim3(kBH, kN / 64), 256, 0, stream>>>(qb, kb, gwb, rdenom, alpha, rcolv);
  k_out  <<<dim3(kBH, kN / 64), 256, 0, stream>>>(qb, kb, vb, gwb, rdenom, rcolv, alpha, ctx);
  k_proj <<<dim3(768 / 128, 4096 / 128), 256, 0, stream>>>(ctx, Wproj, bproj, out);
}

// Round 2
// 1400.100 us; speedup vs baseline: 3.9635x; 3.9635x over previous
//
#include <hip/hip_runtime.h>
#include <math.h>

namespace {

constexpr int kB   = 4;
constexpr int kN   = 1024;
constexpr int kDim = 768;
constexpr int kH   = 12;
constexpr int kGP  = 64;
constexpr int kHD  = 64;
constexpr int kBH  = kB * kH;
constexpr float kScale = 0.125f;  // HD^-0.5

// ---------- swizzled 64x64 f32 LDS tile (flat 4096 floats) ----------
// element (r, d) lives at r*64 + ((d/4) ^ (r&15))*4 + (d&3)
__device__ __forceinline__ int swz(int r, int d) {
  return (r << 6) + (((((d >> 2) ^ (r & 15))) << 2) | (d & 3));
}

__device__ __forceinline__ void load_tile64(float* dst, const float* __restrict__ src, int tid) {
  #pragma unroll
  for (int t = tid; t < 1024; t += 256) {
    const int r = t >> 4;
    const int c = (t & 15) << 2;
    const float4 v4 = *(const float4*)(src + (r << 6) + c);
    *(float4*)(dst + swz(r, c)) = v4;
  }
}

// transposed store: dst[d][m] = src[m][d]
__device__ __forceinline__ void load_tile64_T(float* dst, const float* __restrict__ src, int tid) {
  #pragma unroll
  for (int t = tid; t < 1024; t += 256) {
    const int r = t >> 4;          // source row (m)
    const int c = (t & 15) << 2;   // source col (d)
    const float4 v4 = *(const float4*)(src + (r << 6) + c);
    dst[swz(c + 0, r)] = v4.x;
    dst[swz(c + 1, r)] = v4.y;
    dst[swz(c + 2, r)] = v4.z;
    dst[swz(c + 3, r)] = v4.w;
  }
}

// fused dual GEMM over d=0..63 (bounded unroll to cap register pressure):
//   sa[i][j] += rowsQ[ty4+i][d] * colsK[tx4+j][d]
//   ga[i][j] += rowsG[ty4+i][d] * colsGm[tx4+j][d]
__device__ __forceinline__ void dual_gemm_64(const float* qn, const float* gn,
                                             const float* kt, const float* gm,
                                             int ty4, int tx4,
                                             float sa[4][4], float ga[4][4]) {
  #pragma unroll 4
  for (int d0 = 0; d0 < 64; d0 += 4) {
    float4 aq[4], ag[4];
    #pragma unroll
    for (int i = 0; i < 4; i++) {
      aq[i] = *(const float4*)(qn + swz(ty4 + i, d0));
      ag[i] = *(const float4*)(gn + swz(ty4 + i, d0));
    }
    #pragma unroll
    for (int j = 0; j < 4; j++) {
      const float4 bk = *(const float4*)(kt + swz(tx4 + j, d0));
      const float4 eg = *(const float4*)(gm + swz(tx4 + j, d0));
      #pragma unroll
      for (int i = 0; i < 4; i++) {
        sa[i][j] = fmaf(aq[i].x, bk.x, sa[i][j]);
        sa[i][j] = fmaf(aq[i].y, bk.y, sa[i][j]);
        sa[i][j] = fmaf(aq[i].z, bk.z, sa[i][j]);
        sa[i][j] = fmaf(aq[i].w, bk.w, sa[i][j]);
        ga[i][j] = fmaf(ag[i].x, eg.x, ga[i][j]);
        ga[i][j] = fmaf(ag[i].y, eg.y, ga[i][j]);
        ga[i][j] = fmaf(ag[i].z, eg.z, ga[i][j]);
        ga[i][j] = fmaf(ag[i].w, eg.w, ga[i][j]);
      }
    }
  }
}

// ---------------- K1: qkv = x @ W_qkv^T (+bias), scattered to q/k/v heads ---
__global__ __launch_bounds__(256) void k_qkv(const float* __restrict__ X,
                                             const float* __restrict__ W,
                                             const float* __restrict__ bias,
                                             float* __restrict__ qb,
                                             float* __restrict__ kb,
                                             float* __restrict__ vb) {
  __shared__ float As[32][132];
  __shared__ float Bs[32][132];
  const int bx = blockIdx.x;        // 0..17 over 2304 cols
  const int by = blockIdx.y;        // 0..31 over 4096 rows
  const int tid = threadIdx.x;
  const int tx = tid & 15, ty = tid >> 4;
  const int lrow = tid >> 3;
  const int lk = (tid & 7) << 2;
  float acc[8][8] = {};
  #pragma unroll 1
  for (int k0 = 0; k0 < kDim; k0 += 32) {
    __syncthreads();
    #pragma unroll
    for (int rr = 0; rr < 4; rr++) {
      const int row = lrow + (rr << 5);
      const float4 av = *(const float4*)(X + (size_t)(by * 128 + row) * kDim + k0 + lk);
      As[lk + 0][row] = av.x; As[lk + 1][row] = av.y;
      As[lk + 2][row] = av.z; As[lk + 3][row] = av.w;
      const float4 bv = *(const float4*)(W + (size_t)(bx * 128 + row) * kDim + k0 + lk);
      Bs[lk + 0][row] = bv.x; Bs[lk + 1][row] = bv.y;
      Bs[lk + 2][row] = bv.z; Bs[lk + 3][row] = bv.w;
    }
    __syncthreads();
    #pragma unroll 8
    for (int k = 0; k < 32; k++) {
      const float4 a0 = *(const float4*)(&As[k][ty * 8]);
      const float4 a1 = *(const float4*)(&As[k][ty * 8 + 4]);
      const float4 b0 = *(const float4*)(&Bs[k][tx * 8]);
      const float4 b1 = *(const float4*)(&Bs[k][tx * 8 + 4]);
      const float av8[8] = {a0.x, a0.y, a0.z, a0.w, a1.x, a1.y, a1.z, a1.w};
      const float bv8[8] = {b0.x, b0.y, b0.z, b0.w, b1.x, b1.y, b1.z, b1.w};
      #pragma unroll
      for (int i = 0; i < 8; i++)
        #pragma unroll
        for (int j = 0; j < 8; j++)
          acc[i][j] = fmaf(av8[i], bv8[j], acc[i][j]);
    }
  }
  #pragma unroll
  for (int i = 0; i < 8; i++) {
    const int row = by * 128 + ty * 8 + i;
    const int b = row >> 10;
    const int n = row & 1023;
    #pragma unroll
    for (int j = 0; j < 8; j++) {
      const int col = bx * 128 + tx * 8 + j;
      const int part = col / 768;
      const int rem = col - part * 768;
      const int hh = rem >> 6;
      const int d = rem & 63;
      float* dst = (part == 0) ? qb : ((part == 1) ? kb : vb);
      dst[(size_t)((b * kH + hh) * kN + n) * kHD + d] = acc[i][j] + bias[col];
    }
  }
}

// ---------------- K2: gw = softmax(gelu(v @ gp[h]^T)) over GP=64 ------------
__global__ __launch_bounds__(256) void k_gw(const float* __restrict__ vb,
                                            const float* __restrict__ Wgp,
                                            float* __restrict__ gwb) {
  const int bh = blockIdx.x;
  const int h = bh % kH;
  const int n0 = blockIdx.y << 6;
  __shared__ float gps[64][65];
  __shared__ float vs[64][65];
  const int tid = threadIdx.x;
  #pragma unroll
  for (int t = tid; t < 1024; t += 256) {
    const int r = t >> 4;
    const int c = (t & 15) << 2;
    const float4 g4 = *(const float4*)(Wgp + h * 4096 + (r << 6) + c);
    gps[r][c] = g4.x; gps[r][c + 1] = g4.y; gps[r][c + 2] = g4.z; gps[r][c + 3] = g4.w;
    const float4 v4 = *(const float4*)(vb + (size_t)(bh * kN + n0 + r) * kHD + c);
    vs[r][c] = v4.x; vs[r][c + 1] = v4.y; vs[r][c + 2] = v4.z; vs[r][c + 3] = v4.w;
  }
  __syncthreads();
  const int w = tid >> 6;
  const int lane = tid & 63;
  #pragma unroll 1
  for (int r = 0; r < 16; r++) {
    const int nl = (w << 4) + r;
    float acc = 0.f;
    #pragma unroll
    for (int d = 0; d < 64; d++) acc = fmaf(vs[nl][d], gps[lane][d], acc);
    const float u = 0.5f * acc * (1.0f + erff(acc * 0.70710678118654752f));  // exact GELU
    float mx = u;
    #pragma unroll
    for (int off = 32; off; off >>= 1) mx = fmaxf(mx, __shfl_xor(mx, off));
    const float e = __expf(u - mx);
    float s = e;
    #pragma unroll
    for (int off = 32; off; off >>= 1) s += __shfl_xor(s, off);
    gwb[(size_t)(bh * kN + n0 + nl) * kGP + lane] = e / s;
  }
}

// ---------------- K3: rdenom[n] = 1 / sum_m exp(scale*(q.k)*(gw.gw)) --------
__global__ __launch_bounds__(256) void k_denom(const float* __restrict__ qb,
                                               const float* __restrict__ kb,
                                               const float* __restrict__ gwb,
                                               float* __restrict__ rdenom) {
  const int bh = blockIdx.x;
  const int n0 = blockIdx.y << 6;
  __shared__ float qn[4096], gn[4096], kt[4096], gm[4096];
  const int tid = threadIdx.x;
  const int tx4 = (tid & 15) << 2, ty4 = (tid >> 4) << 2;

  load_tile64(qn, qb + (size_t)(bh * kN + n0) * kHD, tid);
  load_tile64(gn, gwb + (size_t)(bh * kN + n0) * kGP, tid);

  float dsum[4] = {};
  #pragma unroll 1
  for (int m0 = 0; m0 < kN; m0 += 64) {
    __syncthreads();
    load_tile64(kt, kb + (size_t)(bh * kN + m0) * kHD, tid);
    load_tile64(gm, gwb + (size_t)(bh * kN + m0) * kGP, tid);
    __syncthreads();
    float sa[4][4] = {}, ga[4][4] = {};
    dual_gemm_64(qn, gn, kt, gm, ty4, tx4, sa, ga);
    #pragma unroll
    for (int i = 0; i < 4; i++)
      #pragma unroll
      for (int j = 0; j < 4; j++)
        dsum[i] += __expf(sa[i][j] * kScale * ga[i][j]);
  }
  __syncthreads();
  #pragma unroll
  for (int i = 0; i < 4; i++) kt[(ty4 + i) * 16 + (tid & 15)] = dsum[i];
  __syncthreads();
  if (tid < 64) {
    float s = 0.f;
    #pragma unroll
    for (int x = 0; x < 16; x++) s += kt[tid * 16 + x];
    rdenom[bh * kN + n0 + tid] = 1.0f / s;
  }
}

// ---------------- K4: rcol[m] = 1 / (sum_n A[n,m] + 1e-8) -------------------
__global__ __launch_bounds__(256) void k_colsum(const float* __restrict__ qb,
                                                const float* __restrict__ kb,
                                                const float* __restrict__ gwb,
                                                const float* __restrict__ rdenom,
                                                const float* __restrict__ alpha,
                                                float* __restrict__ rcolv) {
  const int bh = blockIdx.x;
  const int h = bh % kH;
  const int m0 = blockIdx.y << 6;
  __shared__ float kt[4096], gm[4096], qn[4096], gn[4096];
  __shared__ float rd[64];
  const int tid = threadIdx.x;
  const int tx4 = (tid & 15) << 2, ty4 = (tid >> 4) << 2;
  const float ah = 1.0f / (1.0f + __expf(-alpha[h]));
  const float om = 1.0f - ah;

  load_tile64(kt, kb + (size_t)(bh * kN + m0) * kHD, tid);
  load_tile64(gm, gwb + (size_t)(bh * kN + m0) * kGP, tid);

  float csum[4] = {};
  #pragma unroll 1
  for (int r0 = 0; r0 < kN; r0 += 64) {
    __syncthreads();
    load_tile64(qn, qb + (size_t)(bh * kN + r0) * kHD, tid);
    load_tile64(gn, gwb + (size_t)(bh * kN + r0) * kGP, tid);
    if (tid < 64) rd[tid] = rdenom[bh * kN + r0 + tid];
    __syncthreads();
    float sa[4][4] = {}, ga[4][4] = {};
    dual_gemm_64(qn, gn, kt, gm, ty4, tx4, sa, ga);
    #pragma unroll
    for (int i = 0; i < 4; i++) {
      const float rdi = rd[ty4 + i];
      #pragma unroll
      for (int j = 0; j < 4; j++) {
        const float g = ga[i][j];
        const float p = __expf(sa[i][j] * kScale * g) * rdi;
        csum[j] += om * p + ah * g;
      }
    }
  }
  __syncthreads();
  #pragma unroll
  for (int j = 0; j < 4; j++) qn[(tx4 + j) * 16 + (tid >> 4)] = csum[j];
  __syncthreads();
  if (tid < 64) {
    float s = 0.f;
    #pragma unroll
    for (int x = 0; x < 16; x++) s += qn[tid * 16 + x];
    rcolv[bh * kN + m0 + tid] = 1.0f / (s + 1e-8f);
  }
}

// ---------------- K5: ctx[b,n,h*64+d] = sum_m (A[n,m]*rcol[m]) * v[m,d] -----
__global__ __launch_bounds__(256) void k_out(const float* __restrict__ qb,
                                             const float* __restrict__ kb,
                                             const float* __restrict__ vb,
                                             const float* __restrict__ gwb,
                                             const float* __restrict__ rdenom,
                                             const float* __restrict__ rcolv,
                                             const float* __restrict__ alpha,
                                             float* __restrict__ ctx) {
  const int bh = blockIdx.x;
  const int h = bh % kH;
  const int b = bh / kH;
  const int n0 = blockIdx.y << 6;
  __shared__ float qn[4096], gn[4096], tC[4096], tD[4096];
  __shared__ float rcl[64];
  const int tid = threadIdx.x;
  const int tx4 = (tid & 15) << 2, ty4 = (tid >> 4) << 2;
  const float ah = 1.0f / (1.0f + __expf(-alpha[h]));
  const float om = 1.0f - ah;

  load_tile64(qn, qb + (size_t)(bh * kN + n0) * kHD, tid);
  load_tile64(gn, gwb + (size_t)(bh * kN + n0) * kGP, tid);
  float rdn[4];
  #pragma unroll
  for (int i = 0; i < 4; i++) rdn[i] = rdenom[bh * kN + n0 + ty4 + i];

  float oacc[4][4] = {};
  #pragma unroll 1
  for (int m0 = 0; m0 < kN; m0 += 64) {
    __syncthreads();
    load_tile64(tC, kb + (size_t)(bh * kN + m0) * kHD, tid);   // K rows
    load_tile64(tD, gwb + (size_t)(bh * kN + m0) * kGP, tid);  // gw_m rows
    if (tid < 64) rcl[tid] = rcolv[bh * kN + m0 + tid];
    __syncthreads();
    float sa[4][4] = {}, ga[4][4] = {};
    dual_gemm_64(qn, gn, tC, tD, ty4, tx4, sa, ga);
    __syncthreads();
    // tC := v^T tile; tD := A*rcol tile (both operands of phase-2 GEMM)
    load_tile64_T(tC, vb + (size_t)(bh * kN + m0) * kHD, tid);
    #pragma unroll
    for (int i = 0; i < 4; i++)
      #pragma unroll
      for (int j = 0; j < 4; j++) {
        const float g = ga[i][j];
        const float p = __expf(sa[i][j] * kScale * g) * rdn[i];
        tD[swz(ty4 + i, tx4 + j)] = (om * p + ah * g) * rcl[tx4 + j];
      }
    __syncthreads();
    #pragma unroll 4
    for (int mm = 0; mm < 64; mm += 4) {
      float4 a4[4], v4[4];
      #pragma unroll
      for (int i = 0; i < 4; i++) a4[i] = *(const float4*)(tD + swz(ty4 + i, mm));
      #pragma unroll
      for (int j = 0; j < 4; j++) v4[j] = *(const float4*)(tC + swz(tx4 + j, mm));
      #pragma unroll
      for (int i = 0; i < 4; i++)
        #pragma unroll
        for (int j = 0; j < 4; j++) {
          oacc[i][j] = fmaf(a4[i].x, v4[j].x, oacc[i][j]);
          oacc[i][j] = fmaf(a4[i].y, v4[j].y, oacc[i][j]);
          oacc[i][j] = fmaf(a4[i].z, v4[j].z, oacc[i][j]);
          oacc[i][j] = fmaf(a4[i].w, v4[j].w, oacc[i][j]);
        }
    }
  }
  #pragma unroll
  for (int i = 0; i < 4; i++) {
    const int n = n0 + ty4 + i;
    float4 o4 = make_float4(oacc[i][0], oacc[i][1], oacc[i][2], oacc[i][3]);
    *(float4*)(ctx + (size_t)(b * kN + n) * kDim + h * kHD + tx4) = o4;
  }
}

// ---------------- K6: out = ctx @ W_proj^T + b_proj -------------------------
__global__ __launch_bounds__(256) void k_proj(const float* __restrict__ Xc,
                                              const float* __restrict__ W,
                                              const float* __restrict__ bias,
                                              float* __restrict__ out) {
  __shared__ float As[32][132];
  __shared__ float Bs[32][132];
  const int bx = blockIdx.x;  // 0..5 over 768 cols
  const int by = blockIdx.y;  // 0..31 over 4096 rows
  const int tid = threadIdx.x;
  const int tx = tid & 15, ty = tid >> 4;
  const int lrow = tid >> 3;
  const int lk = (tid & 7) << 2;
  float acc[8][8] = {};
  #pragma unroll 1
  for (int k0 = 0; k0 < kDim; k0 += 32) {
    __syncthreads();
    #pragma unroll
    for (int rr = 0; rr < 4; rr++) {
      const int row = lrow + (rr << 5);
      const float4 av = *(const float4*)(Xc + (size_t)(by * 128 + row) * kDim + k0 + lk);
      As[lk + 0][row] = av.x; As[lk + 1][row] = av.y;
      As[lk + 2][row] = av.z; As[lk + 3][row] = av.w;
      const float4 bv = *(const float4*)(W + (size_t)(bx * 128 + row) * kDim + k0 + lk);
      Bs[lk + 0][row] = bv.x; Bs[lk + 1][row] = bv.y;
      Bs[lk + 2][row] = bv.z; Bs[lk + 3][row] = bv.w;
    }
    __syncthreads();
    #pragma unroll 8
    for (int k = 0; k < 32; k++) {
      const float4 a0 = *(const float4*)(&As[k][ty * 8]);
      const float4 a1 = *(const float4*)(&As[k][ty * 8 + 4]);
      const float4 b0 = *(const float4*)(&Bs[k][tx * 8]);
      const float4 b1 = *(const float4*)(&Bs[k][tx * 8 + 4]);
      const float av8[8] = {a0.x, a0.y, a0.z, a0.w, a1.x, a1.y, a1.z, a1.w};
      const float bv8[8] = {b0.x, b0.y, b0.z, b0.w, b1.x, b1.y, b1.z, b1.w};
      #pragma unroll
      for (int i = 0; i < 8; i++)
        #pragma unroll
        for (int j = 0; j < 8; j++)
          acc[i][j] = fmaf(av8[i], bv8[j], acc[i][j]);
    }
  }
  #pragma unroll
  for (int i = 0; i < 8; i++) {
    const int row = by * 128 + ty * 8 + i;
    #pragma unroll
    for (int j = 0; j < 8; j++) {
      const int col = bx * 128 + tx * 8 + j;
      out[(size_t)row * kDim + col] = acc[i][j] + bias[col];
    }
  }
}

}  // namespace

extern "C" void kernel_launch(void* const* d_in, const int* in_sizes, int n_in,
                              void* d_out, int out_size, void* d_ws, size_t ws_size,
                              hipStream_t stream) {
  const float* x     = (const float*)d_in[0];
  const float* Wqkv  = (const float*)d_in[1];
  const float* bqkv  = (const float*)d_in[2];
  const float* Wgp   = (const float*)d_in[3];
  const float* alpha = (const float*)d_in[4];
  const float* Wproj = (const float*)d_in[5];
  const float* bproj = (const float*)d_in[6];
  float* out = (float*)d_out;
  float* ws  = (float*)d_ws;

  const size_t head_elems = (size_t)kBH * kN * kHD;  // 3,145,728
  float* qb     = ws;
  float* kb     = qb + head_elems;
  float* vb     = kb + head_elems;
  float* gwb    = vb + head_elems;
  float* rdenom = gwb + head_elems;
  float* rcolv  = rdenom + (size_t)kBH * kN;
  float* ctx    = rcolv + (size_t)kBH * kN;
  // total ws use: ~63.3 MB

  k_qkv  <<<dim3(2304 / 128, 4096 / 128), 256, 0, stream>>>(x, Wqkv, bqkv, qb, kb, vb);
  k_gw   <<<dim3(kBH, kN / 64), 256, 0, stream>>>(vb, Wgp, gwb);
  k_denom<<<dim3(kBH, kN / 64), 256, 0, stream>>>(qb, kb, gwb, rdenom);
  k_colsum<<<dim3(kBH, kN / 64), 256, 0, stream>>>(qb, kb, gwb, rdenom, alpha, rcolv);
  k_out  <<<dim3(kBH, kN / 64), 256, 0, stream>>>(qb, kb, vb, gwb, rdenom, rcolv, alpha, ctx);
  k_proj <<<dim3(768 / 128, 4096 / 128), 256, 0, stream>>>(ctx, Wproj, bproj, out);
}

// Round 3
// 547.082 us; speedup vs baseline: 10.1434x; 2.5592x over previous
//
#include <hip/hip_runtime.h>
#include <math.h>

namespace {

constexpr int kB   = 4;
constexpr int kN   = 1024;
constexpr int kDim = 768;
constexpr int kH   = 12;
constexpr int kHD  = 64;
constexpr int kBH  = kB * kH;
constexpr float kScale = 0.125f;  // HD^-0.5

typedef __attribute__((ext_vector_type(8))) short short8;
typedef __attribute__((ext_vector_type(4))) float f32x4;

#define MFMA(a, b, c) __builtin_amdgcn_mfma_f32_16x16x32_bf16(a, b, c, 0, 0, 0)

// ---------- bf16 split helpers (round-to-nearest-even) ----------
__device__ __forceinline__ ushort f2bf(float f) {
  uint u = __builtin_bit_cast(uint, f);
  u += 0x7fffu + ((u >> 16) & 1u);
  return (ushort)(u >> 16);
}
__device__ __forceinline__ float bf2f(ushort h) {
  uint u = ((uint)h) << 16;
  return __builtin_bit_cast(float, u);
}
__device__ __forceinline__ void split8(const float* f, short8& hi, short8& lo) {
  #pragma unroll
  for (int i = 0; i < 8; i++) {
    const ushort h = f2bf(f[i]);
    hi[i] = (short)h;
    lo[i] = (short)f2bf(f[i] - bf2f(h));
  }
}

// ---------- swizzled bf16 LDS tiles: [64 rows][64 cols], 16B slot ^= row&7 --
// stage one 64x64 fp32 tile (row stride 64) -> hi/lo bf16 swizzled tiles
__device__ __forceinline__ void stage_hl(short* __restrict__ th, short* __restrict__ tl,
                                         const float* __restrict__ src, int tid) {
  const int r  = tid >> 2;
  const int c0 = (tid & 3) << 4;
  float f[16] __attribute__((aligned(16)));
  *(float4*)(f + 0)  = *(const float4*)(src + (size_t)r * 64 + c0 + 0);
  *(float4*)(f + 4)  = *(const float4*)(src + (size_t)r * 64 + c0 + 4);
  *(float4*)(f + 8)  = *(const float4*)(src + (size_t)r * 64 + c0 + 8);
  *(float4*)(f + 12) = *(const float4*)(src + (size_t)r * 64 + c0 + 12);
  #pragma unroll
  for (int j = 0; j < 2; j++) {
    short8 h, l;
    split8(f + j * 8, h, l);
    const int slot = (((tid & 3) << 1) + j) ^ (r & 7);
    *(short8*)(th + r * 64 + slot * 8) = h;
    *(short8*)(tl + r * 64 + slot * 8) = l;
  }
}

// stage 64x64 V tile transposed -> Vt[d][m] (single bf16, swizzled)
__device__ __forceinline__ void stage_vt(short* __restrict__ vt,
                                         const float* __restrict__ src, int tid) {
  const int r  = tid >> 2;        // m-row
  const int c0 = (tid & 3) << 4;  // d base
  float f[16] __attribute__((aligned(16)));
  *(float4*)(f + 0)  = *(const float4*)(src + (size_t)r * 64 + c0 + 0);
  *(float4*)(f + 4)  = *(const float4*)(src + (size_t)r * 64 + c0 + 4);
  *(float4*)(f + 8)  = *(const float4*)(src + (size_t)r * 64 + c0 + 8);
  *(float4*)(f + 12) = *(const float4*)(src + (size_t)r * 64 + c0 + 12);
  #pragma unroll
  for (int i = 0; i < 16; i++) {
    const int d = c0 + i;
    vt[d * 64 + (((r >> 3) ^ (d & 7)) << 3) + (r & 7)] = (short)f2bf(f[i]);
  }
}

// fragment read: lane's 8 contiguous-k bf16 at (row, chunk = k/8)
__device__ __forceinline__ short8 frag(const short* t, int row, int chunk) {
  return *(const short8*)(t + row * 64 + ((chunk ^ (row & 7)) << 3));
}

// row-side A-fragments straight from global: lane (l&15) picks row, (l>>4) picks 8-chunk
__device__ __forceinline__ void load_afrag(const float* __restrict__ rowp, int lane,
                                           short8 hi[2], short8 lo[2]) {
  const float* p = rowp + ((lane >> 4) << 3);
  #pragma unroll
  for (int s = 0; s < 2; s++) {
    float f[8] __attribute__((aligned(16)));
    *(float4*)(f + 0) = *(const float4*)(p + s * 32 + 0);
    *(float4*)(f + 4) = *(const float4*)(p + s * 32 + 4);
    split8(f, hi[s], lo[s]);
  }
}

// ---------------- K1: qkv = x @ W_qkv^T (+bias), scattered to q/k/v heads ---
__global__ __launch_bounds__(256) void k_qkv(const float* __restrict__ X,
                                             const float* __restrict__ W,
                                             const float* __restrict__ bias,
                                             float* __restrict__ qb,
                                             float* __restrict__ kb,
                                             float* __restrict__ vb) {
  __shared__ float As[32][132];
  __shared__ float Bs[32][132];
  const int bx = blockIdx.x;
  const int by = blockIdx.y;
  const int tid = threadIdx.x;
  const int tx = tid & 15, ty = tid >> 4;
  const int lrow = tid >> 3;
  const int lk = (tid & 7) << 2;
  float acc[8][8] = {};
  #pragma unroll 1
  for (int k0 = 0; k0 < kDim; k0 += 32) {
    __syncthreads();
    #pragma unroll
    for (int rr = 0; rr < 4; rr++) {
      const int row = lrow + (rr << 5);
      const float4 av = *(const float4*)(X + (size_t)(by * 128 + row) * kDim + k0 + lk);
      As[lk + 0][row] = av.x; As[lk + 1][row] = av.y;
      As[lk + 2][row] = av.z; As[lk + 3][row] = av.w;
      const float4 bv = *(const float4*)(W + (size_t)(bx * 128 + row) * kDim + k0 + lk);
      Bs[lk + 0][row] = bv.x; Bs[lk + 1][row] = bv.y;
      Bs[lk + 2][row] = bv.z; Bs[lk + 3][row] = bv.w;
    }
    __syncthreads();
    #pragma unroll 8
    for (int k = 0; k < 32; k++) {
      const float4 a0 = *(const float4*)(&As[k][ty * 8]);
      const float4 a1 = *(const float4*)(&As[k][ty * 8 + 4]);
      const float4 b0 = *(const float4*)(&Bs[k][tx * 8]);
      const float4 b1 = *(const float4*)(&Bs[k][tx * 8 + 4]);
      const float av8[8] = {a0.x, a0.y, a0.z, a0.w, a1.x, a1.y, a1.z, a1.w};
      const float bv8[8] = {b0.x, b0.y, b0.z, b0.w, b1.x, b1.y, b1.z, b1.w};
      #pragma unroll
      for (int i = 0; i < 8; i++)
        #pragma unroll
        for (int j = 0; j < 8; j++)
          acc[i][j] = fmaf(av8[i], bv8[j], acc[i][j]);
    }
  }
  #pragma unroll
  for (int i = 0; i < 8; i++) {
    const int row = by * 128 + ty * 8 + i;
    const int b = row >> 10;
    const int n = row & 1023;
    #pragma unroll
    for (int j = 0; j < 8; j++) {
      const int col = bx * 128 + tx * 8 + j;
      const int part = col / 768;
      const int rem = col - part * 768;
      const int hh = rem >> 6;
      const int d = rem & 63;
      float* dst = (part == 0) ? qb : ((part == 1) ? kb : vb);
      dst[(size_t)((b * kH + hh) * kN + n) * kHD + d] = acc[i][j] + bias[col];
    }
  }
}

// ---------------- K2: gw = softmax(gelu(v @ gp[h]^T)) over GP=64 ------------
__global__ __launch_bounds__(256) void k_gw(const float* __restrict__ vb,
                                            const float* __restrict__ Wgp,
                                            float* __restrict__ gwb) {
  const int bh = blockIdx.x;
  const int h = bh % kH;
  const int n0 = blockIdx.y << 6;
  __shared__ float gps[64][65];
  __shared__ float vs[64][65];
  const int tid = threadIdx.x;
  #pragma unroll
  for (int t = tid; t < 1024; t += 256) {
    const int r = t >> 4;
    const int c = (t & 15) << 2;
    const float4 g4 = *(const float4*)(Wgp + h * 4096 + (r << 6) + c);
    gps[r][c] = g4.x; gps[r][c + 1] = g4.y; gps[r][c + 2] = g4.z; gps[r][c + 3] = g4.w;
    const float4 v4 = *(const float4*)(vb + (size_t)(bh * kN + n0 + r) * kHD + c);
    vs[r][c] = v4.x; vs[r][c + 1] = v4.y; vs[r][c + 2] = v4.z; vs[r][c + 3] = v4.w;
  }
  __syncthreads();
  const int w = tid >> 6;
  const int lane = tid & 63;
  #pragma unroll 1
  for (int r = 0; r < 16; r++) {
    const int nl = (w << 4) + r;
    float acc = 0.f;
    #pragma unroll
    for (int d = 0; d < 64; d++) acc = fmaf(vs[nl][d], gps[lane][d], acc);
    const float u = 0.5f * acc * (1.0f + erff(acc * 0.70710678118654752f));
    float mx = u;
    #pragma unroll
    for (int off = 32; off; off >>= 1) mx = fmaxf(mx, __shfl_xor(mx, off));
    const float e = __expf(u - mx);
    float s = e;
    #pragma unroll
    for (int off = 32; off; off >>= 1) s += __shfl_xor(s, off);
    gwb[(size_t)(bh * kN + n0 + nl) * 64 + lane] = e / s;
  }
}

// ---------------- K3: rdenom[n] = 1 / sum_m exp(scale*(q.k)*(gw.gw)) --------
// MFMA bf16x3: block = 64 n-rows, wave w owns rows [w*16, w*16+16), sweeps all m.
__global__ __launch_bounds__(256) void k_denom(const float* __restrict__ qb,
                                               const float* __restrict__ kb,
                                               const float* __restrict__ gwb,
                                               float* __restrict__ rdenom) {
  const int bh = blockIdx.x;
  const int n0 = blockIdx.y << 6;
  const int tid = threadIdx.x, w = tid >> 6, lane = tid & 63;
  __shared__ __align__(16) short kth[4096], ktl[4096], gmh[4096], gml[4096];

  short8 qh[2], ql[2], gh[2], gl[2];
  {
    const size_t row = (size_t)(bh * kN + n0 + w * 16 + (lane & 15)) * 64;
    load_afrag(qb + row, lane, qh, ql);
    load_afrag(gwb + row, lane, gh, gl);
  }
  float dsum[4] = {0.f, 0.f, 0.f, 0.f};
  #pragma unroll 1
  for (int m0 = 0; m0 < kN; m0 += 64) {
    __syncthreads();
    stage_hl(kth, ktl, kb + (size_t)(bh * kN + m0) * 64, tid);
    stage_hl(gmh, gml, gwb + (size_t)(bh * kN + m0) * 64, tid);
    __syncthreads();
    #pragma unroll
    for (int msub = 0; msub < 4; msub++) {
      f32x4 aS = {0.f, 0.f, 0.f, 0.f}, aG = {0.f, 0.f, 0.f, 0.f};
      #pragma unroll
      for (int s = 0; s < 2; s++) {
        const int row = (msub << 4) + (lane & 15);
        const int ch  = (s << 2) + (lane >> 4);
        const short8 bh_ = frag(kth, row, ch);
        const short8 bl_ = frag(ktl, row, ch);
        const short8 eh_ = frag(gmh, row, ch);
        const short8 el_ = frag(gml, row, ch);
        aS = MFMA(qh[s], bh_, aS); aG = MFMA(gh[s], eh_, aG);
        aS = MFMA(qh[s], bl_, aS); aG = MFMA(gh[s], el_, aG);
        aS = MFMA(ql[s], bh_, aS); aG = MFMA(gl[s], eh_, aG);
      }
      #pragma unroll
      for (int r = 0; r < 4; r++)
        dsum[r] += __expf(aS[r] * kScale * aG[r]);
    }
  }
  #pragma unroll
  for (int r = 0; r < 4; r++) {
    #pragma unroll
    for (int msk = 1; msk < 16; msk <<= 1)
      dsum[r] += __shfl_xor(dsum[r], msk);
  }
  if ((lane & 15) == 0) {
    #pragma unroll
    for (int r = 0; r < 4; r++)
      rdenom[bh * kN + n0 + w * 16 + ((lane >> 4) << 2) + r] = 1.0f / dsum[r];
  }
}

// ---------------- K4: rcol[m] = 1 / (sum_n (om*p + ah*g) + 1e-8) ------------
// A-side = K/Gm rows (m, fixed per block); sweeps n tiles.
__global__ __launch_bounds__(256) void k_colsum(const float* __restrict__ qb,
                                                const float* __restrict__ kb,
                                                const float* __restrict__ gwb,
                                                const float* __restrict__ rdenom,
                                                const float* __restrict__ alpha,
                                                float* __restrict__ rcolv) {
  const int bh = blockIdx.x;
  const int h = bh % kH;
  const int m0b = blockIdx.y << 6;
  const int tid = threadIdx.x, w = tid >> 6, lane = tid & 63;
  __shared__ __align__(16) short qth[4096], qtl[4096], gnh[4096], gnl[4096];
  __shared__ float rdl[64];
  const float ah = 1.0f / (1.0f + __expf(-alpha[h]));
  const float om = 1.0f - ah;

  short8 kh[2], kl[2], gh[2], gl[2];
  {
    const size_t row = (size_t)(bh * kN + m0b + w * 16 + (lane & 15)) * 64;
    load_afrag(kb + row, lane, kh, kl);
    load_afrag(gwb + row, lane, gh, gl);
  }
  float csum[4] = {0.f, 0.f, 0.f, 0.f};
  #pragma unroll 1
  for (int nn0 = 0; nn0 < kN; nn0 += 64) {
    __syncthreads();
    stage_hl(qth, qtl, qb + (size_t)(bh * kN + nn0) * 64, tid);
    stage_hl(gnh, gnl, gwb + (size_t)(bh * kN + nn0) * 64, tid);
    if (tid < 64) rdl[tid] = rdenom[bh * kN + nn0 + tid];
    __syncthreads();
    #pragma unroll
    for (int nsub = 0; nsub < 4; nsub++) {
      f32x4 aS = {0.f, 0.f, 0.f, 0.f}, aG = {0.f, 0.f, 0.f, 0.f};
      #pragma unroll
      for (int s = 0; s < 2; s++) {
        const int row = (nsub << 4) + (lane & 15);
        const int ch  = (s << 2) + (lane >> 4);
        const short8 bh_ = frag(qth, row, ch);
        const short8 bl_ = frag(qtl, row, ch);
        const short8 eh_ = frag(gnh, row, ch);
        const short8 el_ = frag(gnl, row, ch);
        aS = MFMA(kh[s], bh_, aS); aG = MFMA(gh[s], eh_, aG);
        aS = MFMA(kh[s], bl_, aS); aG = MFMA(gh[s], el_, aG);
        aS = MFMA(kl[s], bh_, aS); aG = MFMA(gl[s], eh_, aG);
      }
      const float rd = rdl[(nsub << 4) + (lane & 15)];
      #pragma unroll
      for (int r = 0; r < 4; r++) {
        const float g = aG[r];
        csum[r] += om * (__expf(aS[r] * kScale * g) * rd) + ah * g;
      }
    }
  }
  #pragma unroll
  for (int r = 0; r < 4; r++) {
    #pragma unroll
    for (int msk = 1; msk < 16; msk <<= 1)
      csum[r] += __shfl_xor(csum[r], msk);
  }
  if ((lane & 15) == 0) {
    #pragma unroll
    for (int r = 0; r < 4; r++)
      rcolv[bh * kN + m0b + w * 16 + ((lane >> 4) << 2) + r] = 1.0f / (csum[r] + 1e-8f);
  }
}

// ---------------- K5: ctx = (A*rcol) @ V, A recomputed tile-wise ------------
__global__ __launch_bounds__(256) void k_out(const float* __restrict__ qb,
                                             const float* __restrict__ kb,
                                             const float* __restrict__ vb,
                                             const float* __restrict__ gwb,
                                             const float* __restrict__ rdenom,
                                             const float* __restrict__ rcolv,
                                             const float* __restrict__ alpha,
                                             float* __restrict__ ctx) {
  const int bh = blockIdx.x;
  const int h = bh % kH;
  const int b = bh / kH;
  const int n0 = blockIdx.y << 6;
  const int tid = threadIdx.x, w = tid >> 6, lane = tid & 63;
  __shared__ __align__(16) short kth[4096], ktl[4096], gmh[4096], gml[4096];
  __shared__ __align__(16) short vth[4096];
  __shared__ __align__(16) short pls[4096];  // 4 waves x [16][64]
  __shared__ float rcl[64];
  const float ah = 1.0f / (1.0f + __expf(-alpha[h]));
  const float om = 1.0f - ah;

  short8 qh[2], ql[2], gh[2], gl[2];
  float rdn[4];
  {
    const size_t row = (size_t)(bh * kN + n0 + w * 16 + (lane & 15)) * 64;
    load_afrag(qb + row, lane, qh, ql);
    load_afrag(gwb + row, lane, gh, gl);
    #pragma unroll
    for (int r = 0; r < 4; r++)
      rdn[r] = rdenom[bh * kN + n0 + w * 16 + ((lane >> 4) << 2) + r];
  }
  f32x4 oac[4] = {{0.f,0.f,0.f,0.f},{0.f,0.f,0.f,0.f},{0.f,0.f,0.f,0.f},{0.f,0.f,0.f,0.f}};
  short* pw = pls + w * 1024;

  #pragma unroll 1
  for (int m0 = 0; m0 < kN; m0 += 64) {
    __syncthreads();
    stage_hl(kth, ktl, kb + (size_t)(bh * kN + m0) * 64, tid);
    stage_hl(gmh, gml, gwb + (size_t)(bh * kN + m0) * 64, tid);
    stage_vt(vth, vb + (size_t)(bh * kN + m0) * 64, tid);
    if (tid < 64) rcl[tid] = rcolv[bh * kN + m0 + tid];
    __syncthreads();
    // S/G + P-write (wave-local LDS transpose)
    #pragma unroll
    for (int msub = 0; msub < 4; msub++) {
      f32x4 aS = {0.f, 0.f, 0.f, 0.f}, aG = {0.f, 0.f, 0.f, 0.f};
      #pragma unroll
      for (int s = 0; s < 2; s++) {
        const int row = (msub << 4) + (lane & 15);
        const int ch  = (s << 2) + (lane >> 4);
        const short8 bh_ = frag(kth, row, ch);
        const short8 bl_ = frag(ktl, row, ch);
        const short8 eh_ = frag(gmh, row, ch);
        const short8 el_ = frag(gml, row, ch);
        aS = MFMA(qh[s], bh_, aS); aG = MFMA(gh[s], eh_, aG);
        aS = MFMA(qh[s], bl_, aS); aG = MFMA(gh[s], el_, aG);
        aS = MFMA(ql[s], bh_, aS); aG = MFMA(gl[s], eh_, aG);
      }
      const float rc = rcl[(msub << 4) + (lane & 15)];
      #pragma unroll
      for (int r = 0; r < 4; r++) {
        const float g = aG[r];
        const float p = __expf(aS[r] * kScale * g) * rdn[r];
        const float a = (om * p + ah * g) * rc;
        const int prow = ((lane >> 4) << 2) + r;
        const int pcol = (msub << 4) + (lane & 15);
        pw[prow * 64 + (((pcol >> 3) ^ (prow & 7)) << 3) + (pcol & 7)] = (short)f2bf(a);
      }
    }
    // PV: O[16 n x 64 d] += P[16 x 64m] * V[64m x 64d]   (wave-local P)
    #pragma unroll
    for (int s = 0; s < 2; s++) {
      const short8 pa = frag(pw, lane & 15, (s << 2) + (lane >> 4));
      #pragma unroll
      for (int dsub = 0; dsub < 4; dsub++) {
        const short8 vb_ = frag(vth, (dsub << 4) + (lane & 15), (s << 2) + (lane >> 4));
        oac[dsub] = MFMA(pa, vb_, oac[dsub]);
      }
    }
  }
  #pragma unroll
  for (int dsub = 0; dsub < 4; dsub++) {
    #pragma unroll
    for (int r = 0; r < 4; r++) {
      const int n = n0 + w * 16 + ((lane >> 4) << 2) + r;
      const int d = (dsub << 4) + (lane & 15);
      ctx[(size_t)(b * kN + n) * kDim + h * 64 + d] = oac[dsub][r];
    }
  }
}

// ---------------- K6: out = ctx @ W_proj^T + b_proj -------------------------
__global__ __launch_bounds__(256) void k_proj(const float* __restrict__ Xc,
                                              const float* __restrict__ W,
                                              const float* __restrict__ bias,
                                              float* __restrict__ out) {
  __shared__ float As[32][132];
  __shared__ float Bs[32][132];
  const int bx = blockIdx.x;
  const int by = blockIdx.y;
  const int tid = threadIdx.x;
  const int tx = tid & 15, ty = tid >> 4;
  const int lrow = tid >> 3;
  const int lk = (tid & 7) << 2;
  float acc[8][8] = {};
  #pragma unroll 1
  for (int k0 = 0; k0 < kDim; k0 += 32) {
    __syncthreads();
    #pragma unroll
    for (int rr = 0; rr < 4; rr++) {
      const int row = lrow + (rr << 5);
      const float4 av = *(const float4*)(Xc + (size_t)(by * 128 + row) * kDim + k0 + lk);
      As[lk + 0][row] = av.x; As[lk + 1][row] = av.y;
      As[lk + 2][row] = av.z; As[lk + 3][row] = av.w;
      const float4 bv = *(const float4*)(W + (size_t)(bx * 128 + row) * kDim + k0 + lk);
      Bs[lk + 0][row] = bv.x; Bs[lk + 1][row] = bv.y;
      Bs[lk + 2][row] = bv.z; Bs[lk + 3][row] = bv.w;
    }
    __syncthreads();
    #pragma unroll 8
    for (int k = 0; k < 32; k++) {
      const float4 a0 = *(const float4*)(&As[k][ty * 8]);
      const float4 a1 = *(const float4*)(&As[k][ty * 8 + 4]);
      const float4 b0 = *(const float4*)(&Bs[k][tx * 8]);
      const float4 b1 = *(const float4*)(&Bs[k][tx * 8 + 4]);
      const float av8[8] = {a0.x, a0.y, a0.z, a0.w, a1.x, a1.y, a1.z, a1.w};
      const float bv8[8] = {b0.x, b0.y, b0.z, b0.w, b1.x, b1.y, b1.z, b1.w};
      #pragma unroll
      for (int i = 0; i < 8; i++)
        #pragma unroll
        for (int j = 0; j < 8; j++)
          acc[i][j] = fmaf(av8[i], bv8[j], acc[i][j]);
    }
  }
  #pragma unroll
  for (int i = 0; i < 8; i++) {
    const int row = by * 128 + ty * 8 + i;
    #pragma unroll
    for (int j = 0; j < 8; j++) {
      const int col = bx * 128 + tx * 8 + j;
      out[(size_t)row * kDim + col] = acc[i][j] + bias[col];
    }
  }
}

}  // namespace

extern "C" void kernel_launch(void* const* d_in, const int* in_sizes, int n_in,
                              void* d_out, int out_size, void* d_ws, size_t ws_size,
                              hipStream_t stream) {
  const float* x     = (const float*)d_in[0];
  const float* Wqkv  = (const float*)d_in[1];
  const float* bqkv  = (const float*)d_in[2];
  const float* Wgp   = (const float*)d_in[3];
  const float* alpha = (const float*)d_in[4];
  const float* Wproj = (const float*)d_in[5];
  const float* bproj = (const float*)d_in[6];
  float* out = (float*)d_out;
  float* ws  = (float*)d_ws;

  const size_t head_elems = (size_t)kBH * kN * kHD;  // 3,145,728
  float* qb     = ws;
  float* kb     = qb + head_elems;
  float* vb     = kb + head_elems;
  float* gwb    = vb + head_elems;
  float* rdenom = gwb + head_elems;
  float* rcolv  = rdenom + (size_t)kBH * kN;
  float* ctx    = rcolv + (size_t)kBH * kN;
  // total ws use: ~63.3 MB (unchanged from passing round)

  k_qkv   <<<dim3(2304 / 128, 4096 / 128), 256, 0, stream>>>(x, Wqkv, bqkv, qb, kb, vb);
  k_gw    <<<dim3(kBH, kN / 64), 256, 0, stream>>>(vb, Wgp, gwb);
  k_denom <<<dim3(kBH, kN / 64), 256, 0, stream>>>(qb, kb, gwb, rdenom);
  k_colsum<<<dim3(kBH, kN / 64), 256, 0, stream>>>(qb, kb, gwb, rdenom, alpha, rcolv);
  k_out   <<<dim3(kBH, kN / 64), 256, 0, stream>>>(qb, kb, vb, gwb, rdenom, rcolv, alpha, ctx);
  k_proj  <<<dim3(768 / 128, 4096 / 128), 256, 0, stream>>>(ctx, Wproj, bproj, out);
}

// Round 4
// 297.472 us; speedup vs baseline: 18.6548x; 1.8391x over previous
//
#include <hip/hip_runtime.h>
#include <math.h>

namespace {

constexpr int kN   = 1024;
constexpr int kDim = 768;
constexpr int kH   = 12;
constexpr int kBH  = 48;
constexpr float kScale = 0.125f;  // HD^-0.5

typedef __attribute__((ext_vector_type(8))) short short8;
typedef __attribute__((ext_vector_type(4))) short short4v;
typedef __attribute__((ext_vector_type(4))) float f32x4;

#define MFMA(a, b, c) __builtin_amdgcn_mfma_f32_16x16x32_bf16(a, b, c, 0, 0, 0)

// ---------- bf16 split helpers (round-to-nearest-even) ----------
__device__ __forceinline__ ushort f2bf(float f) {
  uint u = __builtin_bit_cast(uint, f);
  u += 0x7fffu + ((u >> 16) & 1u);
  return (ushort)(u >> 16);
}
__device__ __forceinline__ float bf2f(ushort h) {
  uint u = ((uint)h) << 16;
  return __builtin_bit_cast(float, u);
}

// ---------- swizzled bf16 LDS tiles: rows x 64 cols, 16B slot ^= row&7 ------
// fragment read: lane's 8 contiguous-k bf16 at (row, chunk)
__device__ __forceinline__ short8 frag(const short* t, int row, int chunk) {
  return *(const short8*)(t + row * 64 + ((chunk ^ (row & 7)) << 3));
}

// copy 64-row x 64-col bf16 tile global->LDS (swizzled). stride in shorts.
__device__ __forceinline__ void stage_bf(short* __restrict__ dst,
                                         const short* __restrict__ src,
                                         int tid, int stride) {
  const int r = tid >> 2;
  const int s0 = (tid & 3) << 1;
  #pragma unroll
  for (int j = 0; j < 2; j++) {
    const int s = s0 + j;
    *(short8*)(dst + r * 64 + ((s ^ (r & 7)) << 3)) =
        *(const short8*)(src + (size_t)r * stride + (s << 3));
  }
}

// copy 128-row x 64-col bf16 tile global->LDS (swizzled)
__device__ __forceinline__ void stage128(short* __restrict__ dst,
                                         const short* __restrict__ src,
                                         int tid, int stride) {
  const int r = tid >> 1;
  const int s0 = (tid & 1) << 2;
  #pragma unroll
  for (int j = 0; j < 4; j++) {
    const int s = s0 + j;
    *(short8*)(dst + r * 64 + ((s ^ (r & 7)) << 3)) =
        *(const short8*)(src + (size_t)r * stride + (s << 3));
  }
}

// stage 64x64 bf16 V tile transposed -> Vt[d][m] (swizzled)
__device__ __forceinline__ void stage_vt_bf(short* __restrict__ vt,
                                            const short* __restrict__ src, int tid) {
  const int r  = tid >> 2;        // m-row
  const int c0 = (tid & 3) << 4;  // d base
  const short8 a = *(const short8*)(src + (size_t)r * 64 + c0);
  const short8 b = *(const short8*)(src + (size_t)r * 64 + c0 + 8);
  #pragma unroll
  for (int i = 0; i < 8; i++) {
    int d = c0 + i;
    vt[d * 64 + (((r >> 3) ^ (d & 7)) << 3) + (r & 7)] = a[i];
    d = c0 + 8 + i;
    vt[d * 64 + (((r >> 3) ^ (d & 7)) << 3) + (r & 7)] = b[i];
  }
}

// ---------------- K0: fp32 -> bf16 hi/lo split -------------------------------
__global__ __launch_bounds__(256) void k_split(const float* __restrict__ src,
                                               short* __restrict__ h,
                                               short* __restrict__ l) {
  const size_t i = ((size_t)blockIdx.x * 256 + threadIdx.x) * 4;
  const float4 f = *(const float4*)(src + i);
  const float ff[4] = {f.x, f.y, f.z, f.w};
  short4v hv, lv;
  #pragma unroll
  for (int j = 0; j < 4; j++) {
    const ushort u = f2bf(ff[j]);
    hv[j] = (short)u;
    lv[j] = (short)f2bf(ff[j] - bf2f(u));
  }
  *(short4v*)(h + i) = hv;
  *(short4v*)(l + i) = lv;
}

// ---------------- K1: qkv = x @ W_qkv^T (+bias) via bf16x3 MFMA --------------
__global__ __launch_bounds__(256) void k_qkv(const short* __restrict__ xh,
                                             const short* __restrict__ xl,
                                             const short* __restrict__ wh,
                                             const short* __restrict__ wl,
                                             const float* __restrict__ bias,
                                             short* __restrict__ qh, short* __restrict__ ql,
                                             short* __restrict__ kh, short* __restrict__ kl,
                                             short* __restrict__ vh, short* __restrict__ vl) {
  __shared__ __align__(16) short Ah[8192], Al[8192], Bh[8192], Bl[8192];
  const int bx = blockIdx.x, by = blockIdx.y;
  const int tid = threadIdx.x, w = tid >> 6, lane = tid & 63;
  const int wr = w >> 1, wc = w & 1;
  f32x4 acc[4][4] = {};
  #pragma unroll 1
  for (int k0 = 0; k0 < kDim; k0 += 64) {
    __syncthreads();
    stage128(Ah, xh + (size_t)(by * 128) * kDim + k0, tid, kDim);
    stage128(Al, xl + (size_t)(by * 128) * kDim + k0, tid, kDim);
    stage128(Bh, wh + (size_t)(bx * 128) * kDim + k0, tid, kDim);
    stage128(Bl, wl + (size_t)(bx * 128) * kDim + k0, tid, kDim);
    __syncthreads();
    #pragma unroll
    for (int s = 0; s < 2; s++) {
      const int ch = (s << 2) + (lane >> 4);
      short8 af[4], alf[4], bf_[4], blf[4];
      #pragma unroll
      for (int i = 0; i < 4; i++) {
        const int ar = wr * 64 + i * 16 + (lane & 15);
        af[i]  = frag(Ah, ar, ch);
        alf[i] = frag(Al, ar, ch);
        const int br = wc * 64 + i * 16 + (lane & 15);
        bf_[i] = frag(Bh, br, ch);
        blf[i] = frag(Bl, br, ch);
      }
      #pragma unroll
      for (int i = 0; i < 4; i++)
        #pragma unroll
        for (int j = 0; j < 4; j++) {
          acc[i][j] = MFMA(af[i], bf_[j], acc[i][j]);
          acc[i][j] = MFMA(af[i], blf[j], acc[i][j]);
          acc[i][j] = MFMA(alf[i], bf_[j], acc[i][j]);
        }
    }
  }
  #pragma unroll
  for (int j = 0; j < 4; j++) {
    const int col = bx * 128 + wc * 64 + j * 16 + (lane & 15);
    const int part = col / 768;
    const int rem = col - part * 768;
    const int hh = rem >> 6, d = rem & 63;
    short* dh = (part == 0) ? qh : ((part == 1) ? kh : vh);
    short* dl = (part == 0) ? ql : ((part == 1) ? kl : vl);
    const float bv = bias[col];
    #pragma unroll
    for (int i = 0; i < 4; i++) {
      #pragma unroll
      for (int r = 0; r < 4; r++) {
        const int gr = by * 128 + wr * 64 + i * 16 + ((lane >> 4) << 2) + r;
        const int b = gr >> 10, n = gr & 1023;
        const float val = acc[i][j][r] + bv;
        const ushort hu = f2bf(val);
        const size_t idx = (size_t)((b * kH + hh) * kN + n) * 64 + d;
        dh[idx] = (short)hu;
        dl[idx] = (short)f2bf(val - bf2f(hu));
      }
    }
  }
}

// ---------------- K2: gw = softmax(gelu(v @ gp[h]^T)), written as hi/lo -----
__global__ __launch_bounds__(256) void k_gw(const short* __restrict__ vh,
                                            const short* __restrict__ vl,
                                            const float* __restrict__ Wgp,
                                            short* __restrict__ gwh,
                                            short* __restrict__ gwl) {
  const int bh = blockIdx.x;
  const int h = bh % kH;
  const int n0 = blockIdx.y << 6;
  __shared__ float gps[64][65];
  __shared__ float vs[64][65];
  const int tid = threadIdx.x;
  #pragma unroll
  for (int t = tid; t < 1024; t += 256) {
    const int r = t >> 4;
    const int c = (t & 15) << 2;
    const float4 g4 = *(const float4*)(Wgp + h * 4096 + (r << 6) + c);
    gps[r][c] = g4.x; gps[r][c + 1] = g4.y; gps[r][c + 2] = g4.z; gps[r][c + 3] = g4.w;
    const short4v hv = *(const short4v*)(vh + (size_t)(bh * kN + n0 + r) * 64 + c);
    const short4v lv = *(const short4v*)(vl + (size_t)(bh * kN + n0 + r) * 64 + c);
    #pragma unroll
    for (int i = 0; i < 4; i++)
      vs[r][c + i] = bf2f((ushort)hv[i]) + bf2f((ushort)lv[i]);
  }
  __syncthreads();
  const int w = tid >> 6;
  const int lane = tid & 63;
  #pragma unroll 1
  for (int r = 0; r < 16; r++) {
    const int nl = (w << 4) + r;
    float acc = 0.f;
    #pragma unroll
    for (int d = 0; d < 64; d++) acc = fmaf(vs[nl][d], gps[lane][d], acc);
    const float u = 0.5f * acc * (1.0f + erff(acc * 0.70710678118654752f));
    float mx = u;
    #pragma unroll
    for (int off = 32; off; off >>= 1) mx = fmaxf(mx, __shfl_xor(mx, off));
    const float e = __expf(u - mx);
    float s = e;
    #pragma unroll
    for (int off = 32; off; off >>= 1) s += __shfl_xor(s, off);
    const float g = e / s;
    const ushort hu = f2bf(g);
    const size_t idx = (size_t)(bh * kN + n0 + nl) * 64 + lane;
    gwh[idx] = (short)hu;
    gwl[idx] = (short)f2bf(g - bf2f(hu));
  }
}

// ---------------- K3: rdenom[n] = 1 / sum_m exp(scale*(q.k)*(gw.gw)) --------
__global__ __launch_bounds__(256) void k_denom(const short* __restrict__ qh,
                                               const short* __restrict__ ql,
                                               const short* __restrict__ kh,
                                               const short* __restrict__ kl,
                                               const short* __restrict__ gwh,
                                               const short* __restrict__ gwl,
                                               float* __restrict__ rdenom) {
  const int bh = blockIdx.x;
  const int n0 = blockIdx.y << 6;
  const int tid = threadIdx.x, w = tid >> 6, lane = tid & 63;
  __shared__ __align__(16) short kth[4096], ktl[4096], gmh[4096], gml[4096];

  short8 qhf[2], qlf[2], ghf[2], glf[2];
  {
    const size_t arow = (size_t)(bh * kN + n0 + w * 16 + (lane & 15)) * 64 + ((lane >> 4) << 3);
    qhf[0] = *(const short8*)(qh + arow);  qhf[1] = *(const short8*)(qh + arow + 32);
    qlf[0] = *(const short8*)(ql + arow);  qlf[1] = *(const short8*)(ql + arow + 32);
    ghf[0] = *(const short8*)(gwh + arow); ghf[1] = *(const short8*)(gwh + arow + 32);
    glf[0] = *(const short8*)(gwl + arow); glf[1] = *(const short8*)(gwl + arow + 32);
  }
  float dsum[4] = {0.f, 0.f, 0.f, 0.f};
  #pragma unroll 1
  for (int m0 = 0; m0 < kN; m0 += 64) {
    __syncthreads();
    stage_bf(kth, kh + (size_t)(bh * kN + m0) * 64, tid, 64);
    stage_bf(ktl, kl + (size_t)(bh * kN + m0) * 64, tid, 64);
    stage_bf(gmh, gwh + (size_t)(bh * kN + m0) * 64, tid, 64);
    stage_bf(gml, gwl + (size_t)(bh * kN + m0) * 64, tid, 64);
    __syncthreads();
    #pragma unroll
    for (int msub = 0; msub < 4; msub++) {
      f32x4 aS = {0.f, 0.f, 0.f, 0.f}, aG = {0.f, 0.f, 0.f, 0.f};
      #pragma unroll
      for (int s = 0; s < 2; s++) {
        const int row = (msub << 4) + (lane & 15);
        const int ch  = (s << 2) + (lane >> 4);
        const short8 bh_ = frag(kth, row, ch);
        const short8 bl_ = frag(ktl, row, ch);
        const short8 eh_ = frag(gmh, row, ch);
        const short8 el_ = frag(gml, row, ch);
        aS = MFMA(qhf[s], bh_, aS); aG = MFMA(ghf[s], eh_, aG);
        aS = MFMA(qhf[s], bl_, aS); aG = MFMA(ghf[s], el_, aG);
        aS = MFMA(qlf[s], bh_, aS); aG = MFMA(glf[s], eh_, aG);
      }
      #pragma unroll
      for (int r = 0; r < 4; r++)
        dsum[r] += __expf(aS[r] * kScale * aG[r]);
    }
  }
  #pragma unroll
  for (int r = 0; r < 4; r++) {
    #pragma unroll
    for (int msk = 1; msk < 16; msk <<= 1)
      dsum[r] += __shfl_xor(dsum[r], msk);
  }
  if ((lane & 15) == 0) {
    #pragma unroll
    for (int r = 0; r < 4; r++)
      rdenom[bh * kN + n0 + w * 16 + ((lane >> 4) << 2) + r] = 1.0f / dsum[r];
  }
}

// ---------------- K4: rcol[m] = 1 / (sum_n (om*p + ah*g) + 1e-8) ------------
__global__ __launch_bounds__(256) void k_colsum(const short* __restrict__ qh,
                                                const short* __restrict__ ql,
                                                const short* __restrict__ kh,
                                                const short* __restrict__ kl,
                                                const short* __restrict__ gwh,
                                                const short* __restrict__ gwl,
                                                const float* __restrict__ rdenom,
                                                const float* __restrict__ alpha,
                                                float* __restrict__ rcolv) {
  const int bh = blockIdx.x;
  const int h = bh % kH;
  const int m0b = blockIdx.y << 6;
  const int tid = threadIdx.x, w = tid >> 6, lane = tid & 63;
  __shared__ __align__(16) short qth[4096], qtl[4096], gnh[4096], gnl[4096];
  __shared__ float rdl[64];
  const float ah_ = 1.0f / (1.0f + __expf(-alpha[h]));
  const float om = 1.0f - ah_;

  short8 khf[2], klf[2], ghf[2], glf[2];
  {
    const size_t arow = (size_t)(bh * kN + m0b + w * 16 + (lane & 15)) * 64 + ((lane >> 4) << 3);
    khf[0] = *(const short8*)(kh + arow);  khf[1] = *(const short8*)(kh + arow + 32);
    klf[0] = *(const short8*)(kl + arow);  klf[1] = *(const short8*)(kl + arow + 32);
    ghf[0] = *(const short8*)(gwh + arow); ghf[1] = *(const short8*)(gwh + arow + 32);
    glf[0] = *(const short8*)(gwl + arow); glf[1] = *(const short8*)(gwl + arow + 32);
  }
  float csum[4] = {0.f, 0.f, 0.f, 0.f};
  #pragma unroll 1
  for (int nn0 = 0; nn0 < kN; nn0 += 64) {
    __syncthreads();
    stage_bf(qth, qh + (size_t)(bh * kN + nn0) * 64, tid, 64);
    stage_bf(qtl, ql + (size_t)(bh * kN + nn0) * 64, tid, 64);
    stage_bf(gnh, gwh + (size_t)(bh * kN + nn0) * 64, tid, 64);
    stage_bf(gnl, gwl + (size_t)(bh * kN + nn0) * 64, tid, 64);
    if (tid < 64) rdl[tid] = rdenom[bh * kN + nn0 + tid];
    __syncthreads();
    #pragma unroll
    for (int nsub = 0; nsub < 4; nsub++) {
      f32x4 aS = {0.f, 0.f, 0.f, 0.f}, aG = {0.f, 0.f, 0.f, 0.f};
      #pragma unroll
      for (int s = 0; s < 2; s++) {
        const int row = (nsub << 4) + (lane & 15);
        const int ch  = (s << 2) + (lane >> 4);
        const short8 bh_ = frag(qth, row, ch);
        const short8 bl_ = frag(qtl, row, ch);
        const short8 eh_ = frag(gnh, row, ch);
        const short8 el_ = frag(gnl, row, ch);
        aS = MFMA(khf[s], bh_, aS); aG = MFMA(ghf[s], eh_, aG);
        aS = MFMA(khf[s], bl_, aS); aG = MFMA(ghf[s], el_, aG);
        aS = MFMA(klf[s], bh_, aS); aG = MFMA(glf[s], eh_, aG);
      }
      const float rd = rdl[(nsub << 4) + (lane & 15)];
      #pragma unroll
      for (int r = 0; r < 4; r++) {
        const float g = aG[r];
        csum[r] += om * (__expf(aS[r] * kScale * g) * rd) + ah_ * g;
      }
    }
  }
  #pragma unroll
  for (int r = 0; r < 4; r++) {
    #pragma unroll
    for (int msk = 1; msk < 16; msk <<= 1)
      csum[r] += __shfl_xor(csum[r], msk);
  }
  if ((lane & 15) == 0) {
    #pragma unroll
    for (int r = 0; r < 4; r++)
      rcolv[bh * kN + m0b + w * 16 + ((lane >> 4) << 2) + r] = 1.0f / (csum[r] + 1e-8f);
  }
}

// ---------------- K5: ctx = (A*rcol) @ V -> bf16 hi/lo ----------------------
__global__ __launch_bounds__(256) void k_out(const short* __restrict__ qh,
                                             const short* __restrict__ ql,
                                             const short* __restrict__ kh,
                                             const short* __restrict__ kl,
                                             const short* __restrict__ vh,
                                             const short* __restrict__ gwh,
                                             const short* __restrict__ gwl,
                                             const float* __restrict__ rdenom,
                                             const float* __restrict__ rcolv,
                                             const float* __restrict__ alpha,
                                             short* __restrict__ ctxh,
                                             short* __restrict__ ctxl) {
  const int bh = blockIdx.x;
  const int h = bh % kH;
  const int b = bh / kH;
  const int n0 = blockIdx.y << 6;
  const int tid = threadIdx.x, w = tid >> 6, lane = tid & 63;
  __shared__ __align__(16) short kth[4096], ktl[4096], gmh[4096], gml[4096];
  __shared__ __align__(16) short vth[4096], pls[4096];
  __shared__ float rcl[64];
  const float ah_ = 1.0f / (1.0f + __expf(-alpha[h]));
  const float om = 1.0f - ah_;

  short8 qhf[2], qlf[2], ghf[2], glf[2];
  float rdn[4];
  {
    const size_t arow = (size_t)(bh * kN + n0 + w * 16 + (lane & 15)) * 64 + ((lane >> 4) << 3);
    qhf[0] = *(const short8*)(qh + arow);  qhf[1] = *(const short8*)(qh + arow + 32);
    qlf[0] = *(const short8*)(ql + arow);  qlf[1] = *(const short8*)(ql + arow + 32);
    ghf[0] = *(const short8*)(gwh + arow); ghf[1] = *(const short8*)(gwh + arow + 32);
    glf[0] = *(const short8*)(gwl + arow); glf[1] = *(const short8*)(gwl + arow + 32);
    #pragma unroll
    for (int r = 0; r < 4; r++)
      rdn[r] = rdenom[bh * kN + n0 + w * 16 + ((lane >> 4) << 2) + r];
  }
  f32x4 oac[4] = {{0.f,0.f,0.f,0.f},{0.f,0.f,0.f,0.f},{0.f,0.f,0.f,0.f},{0.f,0.f,0.f,0.f}};
  short* pw = pls + w * 1024;

  #pragma unroll 1
  for (int m0 = 0; m0 < kN; m0 += 64) {
    __syncthreads();
    stage_bf(kth, kh + (size_t)(bh * kN + m0) * 64, tid, 64);
    stage_bf(ktl, kl + (size_t)(bh * kN + m0) * 64, tid, 64);
    stage_bf(gmh, gwh + (size_t)(bh * kN + m0) * 64, tid, 64);
    stage_bf(gml, gwl + (size_t)(bh * kN + m0) * 64, tid, 64);
    stage_vt_bf(vth, vh + (size_t)(bh * kN + m0) * 64, tid);
    if (tid < 64) rcl[tid] = rcolv[bh * kN + m0 + tid];
    __syncthreads();
    #pragma unroll
    for (int msub = 0; msub < 4; msub++) {
      f32x4 aS = {0.f, 0.f, 0.f, 0.f}, aG = {0.f, 0.f, 0.f, 0.f};
      #pragma unroll
      for (int s = 0; s < 2; s++) {
        const int row = (msub << 4) + (lane & 15);
        const int ch  = (s << 2) + (lane >> 4);
        const short8 bh_ = frag(kth, row, ch);
        const short8 bl_ = frag(ktl, row, ch);
        const short8 eh_ = frag(gmh, row, ch);
        const short8 el_ = frag(gml, row, ch);
        aS = MFMA(qhf[s], bh_, aS); aG = MFMA(ghf[s], eh_, aG);
        aS = MFMA(qhf[s], bl_, aS); aG = MFMA(ghf[s], el_, aG);
        aS = MFMA(qlf[s], bh_, aS); aG = MFMA(glf[s], eh_, aG);
      }
      const float rc = rcl[(msub << 4) + (lane & 15)];
      #pragma unroll
      for (int r = 0; r < 4; r++) {
        const float g = aG[r];
        const float p = __expf(aS[r] * kScale * g) * rdn[r];
        const float a = (om * p + ah_ * g) * rc;
        const int prow = ((lane >> 4) << 2) + r;
        const int pcol = (msub << 4) + (lane & 15);
        pw[prow * 64 + (((pcol >> 3) ^ (prow & 7)) << 3) + (pcol & 7)] = (short)f2bf(a);
      }
    }
    #pragma unroll
    for (int s = 0; s < 2; s++) {
      const short8 pa = frag(pw, lane & 15, (s << 2) + (lane >> 4));
      #pragma unroll
      for (int dsub = 0; dsub < 4; dsub++) {
        const short8 vb_ = frag(vth, (dsub << 4) + (lane & 15), (s << 2) + (lane >> 4));
        oac[dsub] = MFMA(pa, vb_, oac[dsub]);
      }
    }
  }
  #pragma unroll
  for (int dsub = 0; dsub < 4; dsub++) {
    #pragma unroll
    for (int r = 0; r < 4; r++) {
      const int n = n0 + w * 16 + ((lane >> 4) << 2) + r;
      const int d = (dsub << 4) + (lane & 15);
      const float val = oac[dsub][r];
      const ushort hu = f2bf(val);
      const size_t idx = (size_t)(b * kN + n) * kDim + h * 64 + d;
      ctxh[idx] = (short)hu;
      ctxl[idx] = (short)f2bf(val - bf2f(hu));
    }
  }
}

// ---------------- K6: out = ctx @ W_proj^T + b_proj via bf16x4 MFMA ---------
__global__ __launch_bounds__(256) void k_proj(const short* __restrict__ ch_,
                                              const short* __restrict__ cl_,
                                              const short* __restrict__ wh,
                                              const short* __restrict__ wl,
                                              const float* __restrict__ bias,
                                              float* __restrict__ out) {
  __shared__ __align__(16) short Ah[4096], Al[4096], Bh[8192], Bl[8192];
  const int bx = blockIdx.x, by = blockIdx.y;
  const int tid = threadIdx.x, w = tid >> 6, lane = tid & 63;
  const int wr = w >> 1, wc = w & 1;
  f32x4 acc[2][4] = {};
  #pragma unroll 1
  for (int k0 = 0; k0 < kDim; k0 += 64) {
    __syncthreads();
    stage_bf(Ah, ch_ + (size_t)(by * 64) * kDim + k0, tid, kDim);
    stage_bf(Al, cl_ + (size_t)(by * 64) * kDim + k0, tid, kDim);
    stage128(Bh, wh + (size_t)(bx * 128) * kDim + k0, tid, kDim);
    stage128(Bl, wl + (size_t)(bx * 128) * kDim + k0, tid, kDim);
    __syncthreads();
    #pragma unroll
    for (int s = 0; s < 2; s++) {
      const int ch = (s << 2) + (lane >> 4);
      short8 af[2], alf[2], bf_[4], blf[4];
      #pragma unroll
      for (int i = 0; i < 2; i++) {
        const int ar = wr * 32 + i * 16 + (lane & 15);
        af[i]  = frag(Ah, ar, ch);
        alf[i] = frag(Al, ar, ch);
      }
      #pragma unroll
      for (int j = 0; j < 4; j++) {
        const int br = wc * 64 + j * 16 + (lane & 15);
        bf_[j] = frag(Bh, br, ch);
        blf[j] = frag(Bl, br, ch);
      }
      #pragma unroll
      for (int i = 0; i < 2; i++)
        #pragma unroll
        for (int j = 0; j < 4; j++) {
          acc[i][j] = MFMA(af[i], bf_[j], acc[i][j]);
          acc[i][j] = MFMA(af[i], blf[j], acc[i][j]);
          acc[i][j] = MFMA(alf[i], bf_[j], acc[i][j]);
          acc[i][j] = MFMA(alf[i], blf[j], acc[i][j]);
        }
    }
  }
  #pragma unroll
  for (int i = 0; i < 2; i++) {
    #pragma unroll
    for (int j = 0; j < 4; j++) {
      const int col = bx * 128 + wc * 64 + j * 16 + (lane & 15);
      const float bv = bias[col];
      #pragma unroll
      for (int r = 0; r < 4; r++) {
        const int row = by * 64 + wr * 32 + i * 16 + ((lane >> 4) << 2) + r;
        out[(size_t)row * kDim + col] = acc[i][j][r] + bv;
      }
    }
  }
}

}  // namespace

extern "C" void kernel_launch(void* const* d_in, const int* in_sizes, int n_in,
                              void* d_out, int out_size, void* d_ws, size_t ws_size,
                              hipStream_t stream) {
  const float* x     = (const float*)d_in[0];
  const float* Wqkv  = (const float*)d_in[1];
  const float* bqkv  = (const float*)d_in[2];
  const float* Wgp   = (const float*)d_in[3];
  const float* alpha = (const float*)d_in[4];
  const float* Wproj = (const float*)d_in[5];
  const float* bproj = (const float*)d_in[6];
  float* out = (float*)d_out;

  // workspace layout: 10 bf16 arrays of 3,145,728 elems + 2 small fp32 arrays
  // aliases: Wq-split lives in gw region (dead before k_gw writes);
  //          ctx reuses x region (x dead after k_qkv);
  //          Wp-split reuses q region (q dead after k_out).
  const size_t he = 3145728;  // 48*1024*64 == 4096*768
  short* s0  = (short*)d_ws;
  short* qh  = s0;
  short* ql  = qh + he;
  short* kh  = ql + he;
  short* kl  = kh + he;
  short* vh  = kl + he;
  short* vl  = vh + he;
  short* gwh = vl + he;
  short* gwl = gwh + he;
  short* xh  = gwl + he;
  short* xl  = xh + he;
  float* rdenom = (float*)(xl + he);
  float* rcolv  = rdenom + (size_t)kBH * kN;
  // total: 10*6.29MB + 0.39MB = 63.3MB

  short* Wqh = gwh;  short* Wql = gwl;   // 1,769,472 elems each (fits in 3.1M)
  short* ctxh = xh;  short* ctxl = xl;
  short* Wph = qh;   short* Wpl = ql;    // 589,824 elems each

  k_split<<<3072, 256, 0, stream>>>(x, xh, xl);          // 3,145,728 / 1024
  k_split<<<1728, 256, 0, stream>>>(Wqkv, Wqh, Wql);     // 1,769,472 / 1024
  k_qkv  <<<dim3(18, 32), 256, 0, stream>>>(xh, xl, Wqh, Wql, bqkv,
                                            qh, ql, kh, kl, vh, vl);
  k_gw   <<<dim3(kBH, 16), 256, 0, stream>>>(vh, vl, Wgp, gwh, gwl);
  k_denom<<<dim3(kBH, 16), 256, 0, stream>>>(qh, ql, kh, kl, gwh, gwl, rdenom);
  k_colsum<<<dim3(kBH, 16), 256, 0, stream>>>(qh, ql, kh, kl, gwh, gwl,
                                              rdenom, alpha, rcolv);
  k_out  <<<dim3(kBH, 16), 256, 0, stream>>>(qh, ql, kh, kl, vh, gwh, gwl,
                                             rdenom, rcolv, alpha, ctxh, ctxl);
  k_split<<<576, 256, 0, stream>>>(Wproj, Wph, Wpl);     // 589,824 / 1024
  k_proj <<<dim3(6, 64), 256, 0, stream>>>(ctxh, ctxl, Wph, Wpl, bproj, out);
}

// Round 5
// 271.929 us; speedup vs baseline: 20.4071x; 1.0939x over previous
//
#include <hip/hip_runtime.h>
#include <math.h>

namespace {

constexpr int kN   = 1024;
constexpr int kDim = 768;
constexpr int kH   = 12;
constexpr int kBH  = 48;
constexpr float kScale = 0.125f;  // HD^-0.5

typedef __attribute__((ext_vector_type(8))) short short8;
typedef __attribute__((ext_vector_type(4))) short short4v;
typedef __attribute__((ext_vector_type(4))) float f32x4;

#define MFMA(a, b, c) __builtin_amdgcn_mfma_f32_16x16x32_bf16(a, b, c, 0, 0, 0)

// ---------- bf16 split helpers (round-to-nearest-even) ----------
__device__ __forceinline__ ushort f2bf(float f) {
  uint u = __builtin_bit_cast(uint, f);
  u += 0x7fffu + ((u >> 16) & 1u);
  return (ushort)(u >> 16);
}
__device__ __forceinline__ float bf2f(ushort h) {
  uint u = ((uint)h) << 16;
  return __builtin_bit_cast(float, u);
}
__device__ __forceinline__ void split8(const float* f, short8& hi, short8& lo) {
  #pragma unroll
  for (int i = 0; i < 8; i++) {
    const ushort h = f2bf(f[i]);
    hi[i] = (short)h;
    lo[i] = (short)f2bf(f[i] - bf2f(h));
  }
}

// ---------- async global->LDS, 16B per lane ----------
__device__ __forceinline__ void gl16(const short* g, short* l) {
  __builtin_amdgcn_global_load_lds(
      (const __attribute__((address_space(1))) void*)g,
      (__attribute__((address_space(3))) void*)l, 16, 0, 0);
}

// swizzled tile layout: LDS[row][slot] (64 cols = 8 slots of 8 shorts),
// content LDS[row][slot] = global[row][chunk = slot ^ (row&7)].
// frag read of chunk ch at row: slot = ch ^ (row&7).
__device__ __forceinline__ short8 frag(const short* t, int row, int chunk) {
  return *(const short8*)(t + row * 64 + ((chunk ^ (row & 7)) << 3));
}

// stage ROWS x 64 bf16 tile via global_load_lds; W waves, wave w, lane l.
// LDS dest is linear (wave-uniform base + lane*16B); global src pre-swizzled.
template<int ROWS, int W>
__device__ __forceinline__ void stage_tile(short* dst, const short* src,
                                           int stride, int w, int l) {
  #pragma unroll
  for (int c = 0; c < ROWS / 8; c += W) {
    const int cc = c + w;
    const int row0 = cc << 3;
    const int row = row0 + (l >> 3);
    const int ch = (l & 7) ^ (row & 7);
    gl16(src + (size_t)row * stride + (ch << 3), dst + row0 * 64);
  }
}

// ---------------- K0: fp32 -> bf16 hi/lo split -------------------------------
__global__ __launch_bounds__(256) void k_split(const float* __restrict__ src,
                                               short* __restrict__ h,
                                               short* __restrict__ l) {
  const size_t i = ((size_t)blockIdx.x * 256 + threadIdx.x) * 4;
  const float4 f = *(const float4*)(src + i);
  const float ff[4] = {f.x, f.y, f.z, f.w};
  short4v hv, lv;
  #pragma unroll
  for (int j = 0; j < 4; j++) {
    const ushort u = f2bf(ff[j]);
    hv[j] = (short)u;
    lv[j] = (short)f2bf(ff[j] - bf2f(u));
  }
  *(short4v*)(h + i) = hv;
  *(short4v*)(l + i) = lv;
}

// ---------------- K1: qkv = x @ W_qkv^T (+bias), bf16x3 MFMA, 2-phase -------
__global__ __launch_bounds__(512) void k_qkv(const short* __restrict__ xh,
                                             const short* __restrict__ xl,
                                             const short* __restrict__ wh,
                                             const short* __restrict__ wl,
                                             const float* __restrict__ bias,
                                             short* __restrict__ qh, short* __restrict__ ql,
                                             short* __restrict__ kh, short* __restrict__ kl,
                                             short* __restrict__ vh, short* __restrict__ vl) {
  __shared__ __align__(16) short sb[2][32768];  // Ah|Al|Bh|Bl, 128x64 each
  const int bx = blockIdx.x, by = blockIdx.y;
  const int tid = threadIdx.x, w = tid >> 6, lane = tid & 63;
  const int wr = w >> 2, wc = w & 3;
  const short* Asrc_h = xh + (size_t)(by * 128) * kDim;
  const short* Asrc_l = xl + (size_t)(by * 128) * kDim;
  const short* Bsrc_h = wh + (size_t)(bx * 128) * kDim;
  const short* Bsrc_l = wl + (size_t)(bx * 128) * kDim;

  f32x4 acc[4][2] = {};
  {
    short* nb = sb[0];
    stage_tile<128, 8>(nb,          Asrc_h, kDim, w, lane);
    stage_tile<128, 8>(nb + 8192,   Asrc_l, kDim, w, lane);
    stage_tile<128, 8>(nb + 16384,  Bsrc_h, kDim, w, lane);
    stage_tile<128, 8>(nb + 24576,  Bsrc_l, kDim, w, lane);
  }
  int p = 0;
  #pragma unroll 1
  for (int t = 0; t < 12; ++t) {
    __syncthreads();
    if (t < 11) {
      const int k0 = (t + 1) * 64;
      short* nb = sb[p ^ 1];
      stage_tile<128, 8>(nb,         Asrc_h + k0, kDim, w, lane);
      stage_tile<128, 8>(nb + 8192,  Asrc_l + k0, kDim, w, lane);
      stage_tile<128, 8>(nb + 16384, Bsrc_h + k0, kDim, w, lane);
      stage_tile<128, 8>(nb + 24576, Bsrc_l + k0, kDim, w, lane);
    }
    const short* cb = sb[p];
    #pragma unroll
    for (int s = 0; s < 2; ++s) {
      const int ch = (s << 2) + (lane >> 4);
      short8 af[4], alf[4], bf_[2], blf[2];
      #pragma unroll
      for (int i = 0; i < 4; i++) {
        const int ar = wr * 64 + i * 16 + (lane & 15);
        af[i]  = frag(cb, ar, ch);
        alf[i] = frag(cb + 8192, ar, ch);
      }
      #pragma unroll
      for (int j = 0; j < 2; j++) {
        const int br = wc * 32 + j * 16 + (lane & 15);
        bf_[j] = frag(cb + 16384, br, ch);
        blf[j] = frag(cb + 24576, br, ch);
      }
      #pragma unroll
      for (int i = 0; i < 4; i++)
        #pragma unroll
        for (int j = 0; j < 2; j++) {
          acc[i][j] = MFMA(af[i], bf_[j], acc[i][j]);
          acc[i][j] = MFMA(af[i], blf[j], acc[i][j]);
          acc[i][j] = MFMA(alf[i], bf_[j], acc[i][j]);
        }
    }
    p ^= 1;
  }
  #pragma unroll
  for (int j = 0; j < 2; j++) {
    const int col = bx * 128 + wc * 32 + j * 16 + (lane & 15);
    const int part = col / 768;
    const int rem = col - part * 768;
    const int hh = rem >> 6, d = rem & 63;
    short* dh = (part == 0) ? qh : ((part == 1) ? kh : vh);
    short* dl = (part == 0) ? ql : ((part == 1) ? kl : vl);
    const float bv = bias[col];
    #pragma unroll
    for (int i = 0; i < 4; i++) {
      #pragma unroll
      for (int r = 0; r < 4; r++) {
        const int gr = by * 128 + wr * 64 + i * 16 + ((lane >> 4) << 2) + r;
        const int b = gr >> 10, n = gr & 1023;
        const float val = acc[i][j][r] + bv;
        const ushort hu = f2bf(val);
        const size_t idx = (size_t)((b * kH + hh) * kN + n) * 64 + d;
        dh[idx] = (short)hu;
        dl[idx] = (short)f2bf(val - bf2f(hu));
      }
    }
  }
}

// ---------------- K2: gw = softmax(gelu(v @ gp^T)) via MFMA x3 --------------
__global__ __launch_bounds__(512) void k_gw(const short* __restrict__ vh,
                                            const short* __restrict__ vl,
                                            const float* __restrict__ Wgp,
                                            short* __restrict__ gwh,
                                            short* __restrict__ gwl) {
  const int bh = blockIdx.x;
  const int h = bh % kH;
  const int n0 = blockIdx.y << 7;
  const int tid = threadIdx.x, w = tid >> 6, lane = tid & 63;
  __shared__ __align__(16) short gph[4096], gpl[4096];
  {
    const int r = tid >> 3, c = tid & 7;
    float f[8] __attribute__((aligned(16)));
    *(float4*)(f + 0) = *(const float4*)(Wgp + h * 4096 + r * 64 + c * 8);
    *(float4*)(f + 4) = *(const float4*)(Wgp + h * 4096 + r * 64 + c * 8 + 4);
    short8 hh, ll;
    split8(f, hh, ll);
    const int slot = c ^ (r & 7);
    *(short8*)(gph + r * 64 + slot * 8) = hh;
    *(short8*)(gpl + r * 64 + slot * 8) = ll;
  }
  short8 vhf[2], vlf[2];
  const size_t arow = (size_t)(bh * kN + n0 + w * 16 + (lane & 15)) * 64 + ((lane >> 4) << 3);
  vhf[0] = *(const short8*)(vh + arow); vhf[1] = *(const short8*)(vh + arow + 32);
  vlf[0] = *(const short8*)(vl + arow); vlf[1] = *(const short8*)(vl + arow + 32);
  __syncthreads();

  f32x4 aU[4] = {};
  #pragma unroll
  for (int msub = 0; msub < 4; msub++) {
    #pragma unroll
    for (int s = 0; s < 2; s++) {
      const int row = (msub << 4) + (lane & 15);
      const int ch = (s << 2) + (lane >> 4);
      const short8 bh_ = frag(gph, row, ch);
      const short8 bl_ = frag(gpl, row, ch);
      aU[msub] = MFMA(vhf[s], bh_, aU[msub]);
      aU[msub] = MFMA(vhf[s], bl_, aU[msub]);
      aU[msub] = MFMA(vlf[s], bh_, aU[msub]);
    }
  }
  #pragma unroll
  for (int r = 0; r < 4; r++) {
    float u[4];
    #pragma unroll
    for (int m = 0; m < 4; m++) {
      const float a = aU[m][r];
      u[m] = 0.5f * a * (1.0f + erff(a * 0.70710678118654752f));
    }
    float mx = fmaxf(fmaxf(u[0], u[1]), fmaxf(u[2], u[3]));
    #pragma unroll
    for (int msk = 1; msk < 16; msk <<= 1) mx = fmaxf(mx, __shfl_xor(mx, msk));
    float e[4], ssum = 0.f;
    #pragma unroll
    for (int m = 0; m < 4; m++) { e[m] = __expf(u[m] - mx); ssum += e[m]; }
    #pragma unroll
    for (int msk = 1; msk < 16; msk <<= 1) ssum += __shfl_xor(ssum, msk);
    const float inv = 1.0f / ssum;
    const int n = n0 + w * 16 + ((lane >> 4) << 2) + r;
    #pragma unroll
    for (int m = 0; m < 4; m++) {
      const float g = e[m] * inv;
      const ushort hu = f2bf(g);
      const size_t idx = (size_t)(bh * kN + n) * 64 + (m << 4) + (lane & 15);
      gwh[idx] = (short)hu;
      gwl[idx] = (short)f2bf(g - bf2f(hu));
    }
  }
}

// ---------------- K2b: vtg[bh][d][n] = vh[bh][n][d] transposed --------------
__global__ __launch_bounds__(256) void k_vt(const short* __restrict__ vh,
                                            short* __restrict__ vtg) {
  const int bh = blockIdx.x;
  const int n0 = blockIdx.y << 6;
  __shared__ short t[64][80];
  const int tid = threadIdx.x;
  {
    const int n = tid >> 2, d0 = (tid & 3) << 4;
    const short8 a = *(const short8*)(vh + (size_t)(bh * kN + n0 + n) * 64 + d0);
    const short8 b = *(const short8*)(vh + (size_t)(bh * kN + n0 + n) * 64 + d0 + 8);
    #pragma unroll
    for (int i = 0; i < 8; ++i) { t[d0 + i][n] = a[i]; t[d0 + 8 + i][n] = b[i]; }
  }
  __syncthreads();
  const int d = tid >> 2, j0 = (tid & 3) << 4;
  short* dst = vtg + (size_t)bh * 65536 + (size_t)d * 1024 + n0 + j0;
  *(short8*)(dst)     = *(const short8*)(&t[d][j0]);
  *(short8*)(dst + 8) = *(const short8*)(&t[d][j0 + 8]);
}

// ---------------- K3: rdenom[n] = 1 / sum_m exp(scale*(q.k)*(gw.gw)) --------
__global__ __launch_bounds__(512) void k_denom(const short* __restrict__ qh,
                                               const short* __restrict__ ql,
                                               const short* __restrict__ kh,
                                               const short* __restrict__ kl,
                                               const short* __restrict__ gwh,
                                               const short* __restrict__ gwl,
                                               float* __restrict__ rdenom) {
  const int bh = blockIdx.x;
  const int n0 = blockIdx.y << 7;
  const int tid = threadIdx.x, w = tid >> 6, lane = tid & 63;
  __shared__ __align__(16) short sb[2][16384];  // kth|ktl|gmh|gml

  short8 qhf[2], qlf[2], ghf[2], glf[2];
  {
    const size_t arow = (size_t)(bh * kN + n0 + w * 16 + (lane & 15)) * 64 + ((lane >> 4) << 3);
    qhf[0] = *(const short8*)(qh + arow);  qhf[1] = *(const short8*)(qh + arow + 32);
    qlf[0] = *(const short8*)(ql + arow);  qlf[1] = *(const short8*)(ql + arow + 32);
    ghf[0] = *(const short8*)(gwh + arow); ghf[1] = *(const short8*)(gwh + arow + 32);
    glf[0] = *(const short8*)(gwl + arow); glf[1] = *(const short8*)(gwl + arow + 32);
  }
  {
    const size_t mo = (size_t)bh * kN * 64;
    short* nb = sb[0];
    stage_tile<64, 8>(nb,         kh + mo, 64, w, lane);
    stage_tile<64, 8>(nb + 4096,  kl + mo, 64, w, lane);
    stage_tile<64, 8>(nb + 8192,  gwh + mo, 64, w, lane);
    stage_tile<64, 8>(nb + 12288, gwl + mo, 64, w, lane);
  }
  float dsum[4] = {0.f, 0.f, 0.f, 0.f};
  int p = 0;
  #pragma unroll 1
  for (int t = 0; t < 16; ++t) {
    __syncthreads();
    if (t < 15) {
      const size_t mo = (size_t)(bh * kN + (t + 1) * 64) * 64;
      short* nb = sb[p ^ 1];
      stage_tile<64, 8>(nb,         kh + mo, 64, w, lane);
      stage_tile<64, 8>(nb + 4096,  kl + mo, 64, w, lane);
      stage_tile<64, 8>(nb + 8192,  gwh + mo, 64, w, lane);
      stage_tile<64, 8>(nb + 12288, gwl + mo, 64, w, lane);
    }
    const short* cb = sb[p];
    #pragma unroll
    for (int msub = 0; msub < 4; msub++) {
      f32x4 aS = {0.f, 0.f, 0.f, 0.f}, aG = {0.f, 0.f, 0.f, 0.f};
      #pragma unroll
      for (int s = 0; s < 2; s++) {
        const int row = (msub << 4) + (lane & 15);
        const int ch = (s << 2) + (lane >> 4);
        const short8 bh_ = frag(cb, row, ch);
        const short8 bl_ = frag(cb + 4096, row, ch);
        const short8 eh_ = frag(cb + 8192, row, ch);
        const short8 el_ = frag(cb + 12288, row, ch);
        aS = MFMA(qhf[s], bh_, aS); aG = MFMA(ghf[s], eh_, aG);
        aS = MFMA(qhf[s], bl_, aS); aG = MFMA(ghf[s], el_, aG);
        aS = MFMA(qlf[s], bh_, aS); aG = MFMA(glf[s], eh_, aG);
      }
      #pragma unroll
      for (int r = 0; r < 4; r++)
        dsum[r] += __expf(aS[r] * kScale * aG[r]);
    }
    p ^= 1;
  }
  #pragma unroll
  for (int r = 0; r < 4; r++) {
    #pragma unroll
    for (int msk = 1; msk < 16; msk <<= 1)
      dsum[r] += __shfl_xor(dsum[r], msk);
  }
  if ((lane & 15) == 0) {
    #pragma unroll
    for (int r = 0; r < 4; r++)
      rdenom[bh * kN + n0 + w * 16 + ((lane >> 4) << 2) + r] = 1.0f / dsum[r];
  }
}

// ---------------- K4: rcol[m] = 1 / (sum_n (om*p + ah*g) + 1e-8) ------------
__global__ __launch_bounds__(512) void k_colsum(const short* __restrict__ qh,
                                                const short* __restrict__ ql,
                                                const short* __restrict__ kh,
                                                const short* __restrict__ kl,
                                                const short* __restrict__ gwh,
                                                const short* __restrict__ gwl,
                                                const float* __restrict__ rdenom,
                                                const float* __restrict__ alpha,
                                                float* __restrict__ rcolv) {
  const int bh = blockIdx.x;
  const int m0b = blockIdx.y << 7;
  const int tid = threadIdx.x, w = tid >> 6, lane = tid & 63;
  __shared__ __align__(16) short sb[2][16384];  // qth|qtl|gnh|gnl
  const float ah_ = 1.0f / (1.0f + __expf(-alpha[bh % kH]));
  const float om = 1.0f - ah_;

  short8 khf[2], klf[2], ghf[2], glf[2];
  {
    const size_t arow = (size_t)(bh * kN + m0b + w * 16 + (lane & 15)) * 64 + ((lane >> 4) << 3);
    khf[0] = *(const short8*)(kh + arow);  khf[1] = *(const short8*)(kh + arow + 32);
    klf[0] = *(const short8*)(kl + arow);  klf[1] = *(const short8*)(kl + arow + 32);
    ghf[0] = *(const short8*)(gwh + arow); ghf[1] = *(const short8*)(gwh + arow + 32);
    glf[0] = *(const short8*)(gwl + arow); glf[1] = *(const short8*)(gwl + arow + 32);
  }
  {
    const size_t no = (size_t)bh * kN * 64;
    short* nb = sb[0];
    stage_tile<64, 8>(nb,         qh + no, 64, w, lane);
    stage_tile<64, 8>(nb + 4096,  ql + no, 64, w, lane);
    stage_tile<64, 8>(nb + 8192,  gwh + no, 64, w, lane);
    stage_tile<64, 8>(nb + 12288, gwl + no, 64, w, lane);
  }
  float csum[4] = {0.f, 0.f, 0.f, 0.f};
  int p = 0;
  #pragma unroll 1
  for (int t = 0; t < 16; ++t) {
    __syncthreads();
    if (t < 15) {
      const size_t no = (size_t)(bh * kN + (t + 1) * 64) * 64;
      short* nb = sb[p ^ 1];
      stage_tile<64, 8>(nb,         qh + no, 64, w, lane);
      stage_tile<64, 8>(nb + 4096,  ql + no, 64, w, lane);
      stage_tile<64, 8>(nb + 8192,  gwh + no, 64, w, lane);
      stage_tile<64, 8>(nb + 12288, gwl + no, 64, w, lane);
    }
    const short* cb = sb[p];
    #pragma unroll
    for (int nsub = 0; nsub < 4; nsub++) {
      f32x4 aS = {0.f, 0.f, 0.f, 0.f}, aG = {0.f, 0.f, 0.f, 0.f};
      #pragma unroll
      for (int s = 0; s < 2; s++) {
        const int row = (nsub << 4) + (lane & 15);
        const int ch = (s << 2) + (lane >> 4);
        const short8 bh_ = frag(cb, row, ch);
        const short8 bl_ = frag(cb + 4096, row, ch);
        const short8 eh_ = frag(cb + 8192, row, ch);
        const short8 el_ = frag(cb + 12288, row, ch);
        aS = MFMA(khf[s], bh_, aS); aG = MFMA(ghf[s], eh_, aG);
        aS = MFMA(khf[s], bl_, aS); aG = MFMA(ghf[s], el_, aG);
        aS = MFMA(klf[s], bh_, aS); aG = MFMA(glf[s], eh_, aG);
      }
      const float rd = rdenom[bh * kN + t * 64 + (nsub << 4) + (lane & 15)];
      #pragma unroll
      for (int r = 0; r < 4; r++) {
        const float g = aG[r];
        csum[r] += om * (__expf(aS[r] * kScale * g) * rd) + ah_ * g;
      }
    }
    p ^= 1;
  }
  #pragma unroll
  for (int r = 0; r < 4; r++) {
    #pragma unroll
    for (int msk = 1; msk < 16; msk <<= 1)
      csum[r] += __shfl_xor(csum[r], msk);
  }
  if ((lane & 15) == 0) {
    #pragma unroll
    for (int r = 0; r < 4; r++)
      rcolv[bh * kN + m0b + w * 16 + ((lane >> 4) << 2) + r] = 1.0f / (csum[r] + 1e-8f);
  }
}

// ---------------- K5: ctx = (A*rcol) @ V, 2-phase prefetch ------------------
__global__ __launch_bounds__(512) void k_out(const short* __restrict__ qh,
                                             const short* __restrict__ ql,
                                             const short* __restrict__ kh,
                                             const short* __restrict__ kl,
                                             const short* __restrict__ vtg,
                                             const short* __restrict__ gwh,
                                             const short* __restrict__ gwl,
                                             const float* __restrict__ rdenom,
                                             const float* __restrict__ rcolv,
                                             const float* __restrict__ alpha,
                                             short* __restrict__ ctxh,
                                             short* __restrict__ ctxl) {
  const int bh = blockIdx.x;
  const int h = bh % kH;
  const int b = bh / kH;
  const int n0 = blockIdx.y << 7;
  const int tid = threadIdx.x, w = tid >> 6, lane = tid & 63;
  __shared__ __align__(16) short sb[2][20480];  // kth|ktl|gmh|gml|vth
  __shared__ __align__(16) short pls[8192];     // 8 waves x [16][64]
  const float ah_ = 1.0f / (1.0f + __expf(-alpha[h]));
  const float om = 1.0f - ah_;

  short8 qhf[2], qlf[2], ghf[2], glf[2];
  float rdn[4];
  {
    const size_t arow = (size_t)(bh * kN + n0 + w * 16 + (lane & 15)) * 64 + ((lane >> 4) << 3);
    qhf[0] = *(const short8*)(qh + arow);  qhf[1] = *(const short8*)(qh + arow + 32);
    qlf[0] = *(const short8*)(ql + arow);  qlf[1] = *(const short8*)(ql + arow + 32);
    ghf[0] = *(const short8*)(gwh + arow); ghf[1] = *(const short8*)(gwh + arow + 32);
    glf[0] = *(const short8*)(gwl + arow); glf[1] = *(const short8*)(gwl + arow + 32);
    #pragma unroll
    for (int r = 0; r < 4; r++)
      rdn[r] = rdenom[bh * kN + n0 + w * 16 + ((lane >> 4) << 2) + r];
  }
  {
    const size_t mo = (size_t)bh * kN * 64;
    short* nb = sb[0];
    stage_tile<64, 8>(nb,         kh + mo, 64, w, lane);
    stage_tile<64, 8>(nb + 4096,  kl + mo, 64, w, lane);
    stage_tile<64, 8>(nb + 8192,  gwh + mo, 64, w, lane);
    stage_tile<64, 8>(nb + 12288, gwl + mo, 64, w, lane);
    stage_tile<64, 8>(nb + 16384, vtg + (size_t)bh * 65536, kN, w, lane);
  }
  f32x4 oac[4] = {{0.f,0.f,0.f,0.f},{0.f,0.f,0.f,0.f},{0.f,0.f,0.f,0.f},{0.f,0.f,0.f,0.f}};
  short* pw = pls + w * 1024;
  int p = 0;
  #pragma unroll 1
  for (int t = 0; t < 16; ++t) {
    __syncthreads();
    if (t < 15) {
      const size_t mo = (size_t)(bh * kN + (t + 1) * 64) * 64;
      short* nb = sb[p ^ 1];
      stage_tile<64, 8>(nb,         kh + mo, 64, w, lane);
      stage_tile<64, 8>(nb + 4096,  kl + mo, 64, w, lane);
      stage_tile<64, 8>(nb + 8192,  gwh + mo, 64, w, lane);
      stage_tile<64, 8>(nb + 12288, gwl + mo, 64, w, lane);
      stage_tile<64, 8>(nb + 16384, vtg + (size_t)bh * 65536 + (t + 1) * 64, kN, w, lane);
    }
    const short* cb = sb[p];
    #pragma unroll
    for (int msub = 0; msub < 4; msub++) {
      f32x4 aS = {0.f, 0.f, 0.f, 0.f}, aG = {0.f, 0.f, 0.f, 0.f};
      #pragma unroll
      for (int s = 0; s < 2; s++) {
        const int row = (msub << 4) + (lane & 15);
        const int ch = (s << 2) + (lane >> 4);
        const short8 bh_ = frag(cb, row, ch);
        const short8 bl_ = frag(cb + 4096, row, ch);
        const short8 eh_ = frag(cb + 8192, row, ch);
        const short8 el_ = frag(cb + 12288, row, ch);
        aS = MFMA(qhf[s], bh_, aS); aG = MFMA(ghf[s], eh_, aG);
        aS = MFMA(qhf[s], bl_, aS); aG = MFMA(ghf[s], el_, aG);
        aS = MFMA(qlf[s], bh_, aS); aG = MFMA(glf[s], eh_, aG);
      }
      const float rc = rcolv[bh * kN + t * 64 + (msub << 4) + (lane & 15)];
      #pragma unroll
      for (int r = 0; r < 4; r++) {
        const float g = aG[r];
        const float pp = __expf(aS[r] * kScale * g) * rdn[r];
        const float a = (om * pp + ah_ * g) * rc;
        const int prow = ((lane >> 4) << 2) + r;
        const int pcol = (msub << 4) + (lane & 15);
        pw[prow * 64 + (((pcol >> 3) ^ (prow & 7)) << 3) + (pcol & 7)] = (short)f2bf(a);
      }
    }
    #pragma unroll
    for (int s = 0; s < 2; s++) {
      const short8 pa = frag(pw, lane & 15, (s << 2) + (lane >> 4));
      #pragma unroll
      for (int dsub = 0; dsub < 4; dsub++) {
        const short8 vb_ = frag(cb + 16384, (dsub << 4) + (lane & 15), (s << 2) + (lane >> 4));
        oac[dsub] = MFMA(pa, vb_, oac[dsub]);
      }
    }
    p ^= 1;
  }
  #pragma unroll
  for (int dsub = 0; dsub < 4; dsub++) {
    #pragma unroll
    for (int r = 0; r < 4; r++) {
      const int n = n0 + w * 16 + ((lane >> 4) << 2) + r;
      const int d = (dsub << 4) + (lane & 15);
      const float val = oac[dsub][r];
      const ushort hu = f2bf(val);
      const size_t idx = (size_t)(b * kN + n) * kDim + h * 64 + d;
      ctxh[idx] = (short)hu;
      ctxl[idx] = (short)f2bf(val - bf2f(hu));
    }
  }
}

// ---------------- K6: out = ctx @ W_proj^T + b_proj, bf16x4, 2-phase --------
__global__ __launch_bounds__(512) void k_proj(const short* __restrict__ ch_,
                                              const short* __restrict__ cl_,
                                              const short* __restrict__ wh,
                                              const short* __restrict__ wl,
                                              const float* __restrict__ bias,
                                              float* __restrict__ out) {
  __shared__ __align__(16) short sb[2][32768];  // Ah|Al|Bh|Bl, 128x64 each
  const int bx = blockIdx.x, by = blockIdx.y;
  const int tid = threadIdx.x, w = tid >> 6, lane = tid & 63;
  const int wr = w >> 2, wc = w & 3;
  const short* Asrc_h = ch_ + (size_t)(by * 128) * kDim;
  const short* Asrc_l = cl_ + (size_t)(by * 128) * kDim;
  const short* Bsrc_h = wh + (size_t)(bx * 128) * kDim;
  const short* Bsrc_l = wl + (size_t)(bx * 128) * kDim;

  f32x4 acc[4][2] = {};
  {
    short* nb = sb[0];
    stage_tile<128, 8>(nb,         Asrc_h, kDim, w, lane);
    stage_tile<128, 8>(nb + 8192,  Asrc_l, kDim, w, lane);
    stage_tile<128, 8>(nb + 16384, Bsrc_h, kDim, w, lane);
    stage_tile<128, 8>(nb + 24576, Bsrc_l, kDim, w, lane);
  }
  int p = 0;
  #pragma unroll 1
  for (int t = 0; t < 12; ++t) {
    __syncthreads();
    if (t < 11) {
      const int k0 = (t + 1) * 64;
      short* nb = sb[p ^ 1];
      stage_tile<128, 8>(nb,         Asrc_h + k0, kDim, w, lane);
      stage_tile<128, 8>(nb + 8192,  Asrc_l + k0, kDim, w, lane);
      stage_tile<128, 8>(nb + 16384, Bsrc_h + k0, kDim, w, lane);
      stage_tile<128, 8>(nb + 24576, Bsrc_l + k0, kDim, w, lane);
    }
    const short* cb = sb[p];
    #pragma unroll
    for (int s = 0; s < 2; ++s) {
      const int ch = (s << 2) + (lane >> 4);
      short8 af[4], alf[4], bf_[2], blf[2];
      #pragma unroll
      for (int i = 0; i < 4; i++) {
        const int ar = wr * 64 + i * 16 + (lane & 15);
        af[i]  = frag(cb, ar, ch);
        alf[i] = frag(cb + 8192, ar, ch);
      }
      #pragma unroll
      for (int j = 0; j < 2; j++) {
        const int br = wc * 32 + j * 16 + (lane & 15);
        bf_[j] = frag(cb + 16384, br, ch);
        blf[j] = frag(cb + 24576, br, ch);
      }
      #pragma unroll
      for (int i = 0; i < 4; i++)
        #pragma unroll
        for (int j = 0; j < 2; j++) {
          acc[i][j] = MFMA(af[i], bf_[j], acc[i][j]);
          acc[i][j] = MFMA(af[i], blf[j], acc[i][j]);
          acc[i][j] = MFMA(alf[i], bf_[j], acc[i][j]);
          acc[i][j] = MFMA(alf[i], blf[j], acc[i][j]);
        }
    }
    p ^= 1;
  }
  #pragma unroll
  for (int j = 0; j < 2; j++) {
    const int col = bx * 128 + wc * 32 + j * 16 + (lane & 15);
    const float bv = bias[col];
    #pragma unroll
    for (int i = 0; i < 4; i++) {
      #pragma unroll
      for (int r = 0; r < 4; r++) {
        const int row = by * 128 + wr * 64 + i * 16 + ((lane >> 4) << 2) + r;
        out[(size_t)row * kDim + col] = acc[i][j][r] + bv;
      }
    }
  }
}

}  // namespace

extern "C" void kernel_launch(void* const* d_in, const int* in_sizes, int n_in,
                              void* d_out, int out_size, void* d_ws, size_t ws_size,
                              hipStream_t stream) {
  const float* x     = (const float*)d_in[0];
  const float* Wqkv  = (const float*)d_in[1];
  const float* bqkv  = (const float*)d_in[2];
  const float* Wgp   = (const float*)d_in[3];
  const float* alpha = (const float*)d_in[4];
  const float* Wproj = (const float*)d_in[5];
  const float* bproj = (const float*)d_in[6];
  float* out = (float*)d_out;

  // workspace: 10 bf16 regions of 3,145,728 elems + 2 small fp32 (63.3 MB, as
  // validated since R3). Aliases: Wq-split in gw region; vtg in vl region
  // (vl dead after k_gw); ctx in x region; Wp-split in q region.
  const size_t he = 3145728;
  short* qh  = (short*)d_ws;
  short* ql  = qh + he;
  short* kh  = ql + he;
  short* kl  = kh + he;
  short* vh  = kl + he;
  short* vl  = vh + he;
  short* gwh = vl + he;
  short* gwl = gwh + he;
  short* xh  = gwl + he;
  short* xl  = xh + he;
  float* rdenom = (float*)(xl + he);
  float* rcolv  = rdenom + (size_t)kBH * kN;

  short* Wqh = gwh;  short* Wql = gwl;
  short* vtg = vl;           // [48][64][1024], written by k_vt after k_gw
  short* ctxh = xh;  short* ctxl = xl;
  short* Wph = qh;   short* Wpl = ql;

  k_split<<<3072, 256, 0, stream>>>(x, xh, xl);
  k_split<<<1728, 256, 0, stream>>>(Wqkv, Wqh, Wql);
  k_qkv  <<<dim3(18, 32), 512, 0, stream>>>(xh, xl, Wqh, Wql, bqkv,
                                            qh, ql, kh, kl, vh, vl);
  k_gw   <<<dim3(kBH, 8), 512, 0, stream>>>(vh, vl, Wgp, gwh, gwl);
  k_vt   <<<dim3(kBH, 16), 256, 0, stream>>>(vh, vtg);
  k_denom<<<dim3(kBH, 8), 512, 0, stream>>>(qh, ql, kh, kl, gwh, gwl, rdenom);
  k_colsum<<<dim3(kBH, 8), 512, 0, stream>>>(qh, ql, kh, kl, gwh, gwl,
                                             rdenom, alpha, rcolv);
  k_out  <<<dim3(kBH, 8), 512, 0, stream>>>(qh, ql, kh, kl, vtg, gwh, gwl,
                                            rdenom, rcolv, alpha, ctxh, ctxl);
  k_split<<<576, 256, 0, stream>>>(Wproj, Wph, Wpl);
  k_proj <<<dim3(6, 32), 512, 0, stream>>>(ctxh, ctxl, Wph, Wpl, bproj, out);
}